// Round 7
// baseline (201.264 us; speedup 1.0000x reference)
//
#include <hip/hip_runtime.h>
#include <cstdint>
#include <cstddef>

// VarianceAdaptor — R7: m97-style K-loop: B weights staged via global_load_lds
// into a double-buffered LDS tile, counted vmcnt(4) + raw s_barrier per step
// (no vmcnt(0) drain in the loop). 1x4 col wave split. B=64,S=512,T=2048,H=256.

#define HH 256
#define SS 512
#define BB 64
#define TT 2048

typedef __bf16 bf16;
typedef __attribute__((ext_vector_type(8))) __bf16 bf16x8;
typedef __attribute__((ext_vector_type(4))) float f32x4;

static constexpr size_t WSZ  = (size_t)3 * HH * HH;   // elems per conv weight
static constexpr size_t H1SZ = (size_t)BB * SS * HH;  // elems per h1 buffer

// swizzled halfword index into a [rows][256] bf16 LDS tile (row stride 512B).
__device__ __forceinline__ int swz(int r, int c) { return (r * HH + c) ^ ((r & 7) << 3); }

__device__ __forceinline__ void gload16(const void* g, void* l) {
    __builtin_amdgcn_global_load_lds(
        (const __attribute__((address_space(1))) unsigned int*)g,
        (__attribute__((address_space(3))) unsigned int*)l, 16, 0, 0);
}

// ---------------- bucket (searchsorted over jnp.linspace(-2,2,255) edges) ----
__device__ __forceinline__ float edge_val(int j) {
    const float step = 4.0f / 254.0f;
    if (j == 254) return 2.0f;
    return __fadd_rn(-2.0f, __fmul_rn((float)j, step));
}
__device__ __forceinline__ int bucket256(float v) {
    int lo = 0, hi = 255;
    while (lo < hi) {
        int mid = (lo + hi) >> 1;
        if (edge_val(mid) < v) lo = mid + 1; else hi = mid;
    }
    return lo;
}

// -- weight pack: w[k][c][f] f32 -> wp[k][kcb][fb][lane][8] bf16 (16KB/step) --
// B-frag for mfma_16x16x32: lane l holds B[col = fb*16 + (l&15)]
//                                  [c   = kcb*32 + (l>>4)*8 + j], j=0..7
__global__ void wt_pack(const float* __restrict__ w0, const float* __restrict__ w1,
                        const float* __restrict__ w2, const float* __restrict__ w3,
                        const float* __restrict__ w4, const float* __restrict__ w5,
                        bf16* __restrict__ wp) {
    const int cv = blockIdx.x / 3, k = blockIdx.x % 3;
    const float* wsel[6] = {w0, w1, w2, w3, w4, w5};
    const float* wk = wsel[cv] + (size_t)k * HH * HH;   // [c][f]
    bf16* o = wp + ((size_t)(cv * 3 + k)) * HH * HH;
    for (int fb = 0; fb < 16; ++fb) {
        #pragma unroll
        for (int h = 0; h < 2; ++h) {
            const int idx  = threadIdx.x + 256 * h;     // 0..511
            const int kcb  = idx >> 6, lane = idx & 63;
            const int f    = fb * 16 + (lane & 15);
            const int c0   = kcb * 32 + (lane >> 4) * 8;
            bf16x8 v;
            #pragma unroll
            for (int j = 0; j < 8; ++j) v[j] = (bf16)wk[(size_t)(c0 + j) * HH + f];
            *(bf16x8*)(o + (((size_t)kcb * 16 + fb) * 64 + lane) * 8) = v;
        }
    }
}

// ------------- x convert: x1 = bf16(x), x2 = bf16(x + p_table[bucket]) -------
__global__ __launch_bounds__(256) void xcvt_kernel(
    const float* __restrict__ x, const float* __restrict__ pt,
    const float* __restrict__ ptab,
    bf16* __restrict__ x1, bf16* __restrict__ x2)
{
    const int row = blockIdx.x * 8 + (threadIdx.x >> 5);   // 0 .. B*S-1
    const int c   = (threadIdx.x & 31) * 8;
    const int pb  = bucket256(pt[row]);
    const float4 v0 = *(const float4*)(x + (size_t)row * HH + c);
    const float4 v1 = *(const float4*)(x + (size_t)row * HH + c + 4);
    const float4 t0 = *(const float4*)(ptab + (size_t)pb * HH + c);
    const float4 t1 = *(const float4*)(ptab + (size_t)pb * HH + c + 4);
    bf16x8 a, b2;
    a[0] = (bf16)v0.x; a[1] = (bf16)v0.y; a[2] = (bf16)v0.z; a[3] = (bf16)v0.w;
    a[4] = (bf16)v1.x; a[5] = (bf16)v1.y; a[6] = (bf16)v1.z; a[7] = (bf16)v1.w;
    b2[0] = (bf16)(v0.x + t0.x); b2[1] = (bf16)(v0.y + t0.y);
    b2[2] = (bf16)(v0.z + t0.z); b2[3] = (bf16)(v0.w + t0.w);
    b2[4] = (bf16)(v1.x + t1.x); b2[5] = (bf16)(v1.y + t1.y);
    b2[6] = (bf16)(v1.z + t1.z); b2[7] = (bf16)(v1.w + t1.w);
    *(bf16x8*)(x1 + (size_t)row * HH + c) = a;
    *(bf16x8*)(x2 + (size_t)row * HH + c) = b2;
}

// ---------------- merged fused conv (3 predictors in one grid) ---------------
struct Args3 {
    const float* bias[3];
    const float* g[3];
    const float* be[3];
    const float* lw[3];
    const float* lb[3];
    float*       out[3];
};

// grid = 3*512; 256 threads = 4 waves; wave wv owns cols [64wv, 64wv+64),
// all 64 rows. B staged per K-step (16KB) via global_load_lds, double-buffered.
template <bool LIN>
__global__ __launch_bounds__(256, 2) void conv_all(
    const bf16* __restrict__ in01,    // !LIN: x1 ; LIN: h1 base
    const bf16* __restrict__ in2,     // !LIN: x2 (pred 2) ; LIN unused
    const bf16* __restrict__ wpk,     // packed weights, 6 convs
    Args3 args,
    bf16* __restrict__ h1out,         // !LIN output base
    const uint8_t* __restrict__ mask) // LIN only
{
    __shared__ alignas(16) bf16 tile[66 * HH];
    __shared__ alignas(16) bf16 bbuf[2 * 8192];     // 2 x 16KB B step-tiles
    __shared__ float red_s[64][4], red_q[64][4];
    __shared__ float ln_m[64], ln_r[64];

    const int tid    = threadIdx.x;
    const int pred   = blockIdx.x >> 9;
    const int within = blockIdx.x & 511;
    const int b      = within >> 3;
    const int s0     = (within & 7) * 64;

    const int lane = tid & 63;
    const int wv   = tid >> 6;

    const bf16* inb = LIN ? (in01 + (size_t)pred * H1SZ + (size_t)b * SS * HH)
                          : ((pred == 2 ? in2 : in01) + (size_t)b * SS * HH);
    const bf16* wt = wpk + (size_t)(pred * 2 + (LIN ? 1 : 0)) * WSZ;

    // ---- prologue staging: X tile (66 rows, swizzled src) + B step 0 ----
    for (int c = wv; c < 33; c += 4) {
        const int rrow = 2 * c + (lane >> 5);
        const int s    = s0 - 1 + rrow;
        const int sc   = min(max(s, 0), SS - 1);
        const char* src = (const char*)inb + (size_t)sc * 512
                        + (((lane & 31) * 16) ^ ((rrow & 7) << 4));
        gload16(src, (char*)tile + (size_t)c * 1024);
    }
    #pragma unroll
    for (int j = 0; j < 4; ++j) {
        const int c = wv * 4 + j;
        gload16((const char*)wt + c * 1024 + lane * 16, (char*)bbuf + c * 1024);
    }
    __syncthreads();   // one-time full drain: X + B(0) resident
    // halo fixup: zero rows whose source was clamped (batch edges)
    if (tid < 64) {
        if (s0 == 0)       *(uint2*)&tile[tid * 4]           = make_uint2(0u, 0u);
        if (s0 == SS - 64) *(uint2*)&tile[65 * HH + tid * 4] = make_uint2(0u, 0u);
    }
    __syncthreads();

    const int ln15 = lane & 15;
    const int g8   = (lane >> 4) << 3;

    f32x4 acc[4][4];
    #pragma unroll
    for (int nf = 0; nf < 4; ++nf) {
        const float bv = args.bias[pred][wv * 64 + nf * 16 + ln15];
        #pragma unroll
        for (int mf = 0; mf < 4; ++mf) acc[mf][nf] = f32x4{bv, bv, bv, bv};
    }

    // ---- main loop: 24 K-steps, B dbuf, counted vmcnt, raw barrier ----
    #pragma unroll 1
    for (int t = 0; t < 24; ++t) {
        if (t < 23) {
            const char* ws = (const char*)wt + (size_t)(t + 1) * 16384;
            char* bd = (char*)bbuf + ((t + 1) & 1) * 16384;
            #pragma unroll
            for (int j = 0; j < 4; ++j) {
                const int c = wv * 4 + j;
                gload16(ws + c * 1024 + lane * 16, bd + c * 1024);
            }
            asm volatile("s_waitcnt vmcnt(4)" ::: "memory");  // B(t) landed
        } else {
            asm volatile("s_waitcnt vmcnt(0)" ::: "memory");
        }
        __builtin_amdgcn_s_barrier();

        const int k = t >> 3, kcb = t & 7;
        const int kc = kcb << 5;
        bf16x8 a[4], bb[4];
        #pragma unroll
        for (int mf = 0; mf < 4; ++mf)
            a[mf] = *(const bf16x8*)&tile[swz(16 * mf + ln15 + k, kc + g8)];
        const bf16* bp = bbuf + (t & 1) * 8192 + (size_t)(wv * 4) * 512 + (size_t)lane * 8;
        #pragma unroll
        for (int nf = 0; nf < 4; ++nf)
            bb[nf] = *(const bf16x8*)(bp + (size_t)nf * 512);
        #pragma unroll
        for (int mf = 0; mf < 4; ++mf)
            #pragma unroll
            for (int nf = 0; nf < 4; ++nf)
                acc[mf][nf] = __builtin_amdgcn_mfma_f32_16x16x32_bf16(
                    a[mf], bb[nf], acc[mf][nf], 0, 0, 0);
    }

    // ReLU
    #pragma unroll
    for (int mf = 0; mf < 4; ++mf)
        #pragma unroll
        for (int nf = 0; nf < 4; ++nf)
            #pragma unroll
            for (int i = 0; i < 4; ++i)
                acc[mf][nf][i] = fmaxf(acc[mf][nf][i], 0.f);

    // LN cross-wave reduce
    #pragma unroll
    for (int mf = 0; mf < 4; ++mf) {
        #pragma unroll
        for (int i = 0; i < 4; ++i) {
            float s = acc[mf][0][i] + acc[mf][1][i] + acc[mf][2][i] + acc[mf][3][i];
            float q = acc[mf][0][i] * acc[mf][0][i] + acc[mf][1][i] * acc[mf][1][i] +
                      acc[mf][2][i] * acc[mf][2][i] + acc[mf][3][i] * acc[mf][3][i];
            #pragma unroll
            for (int off = 1; off < 16; off <<= 1) {
                s += __shfl_xor(s, off);
                q += __shfl_xor(q, off);
            }
            if (ln15 == 0) {
                const int row = 16 * mf + (lane >> 4) * 4 + i;
                red_s[row][wv] = s;
                red_q[row][wv] = q;
            }
        }
    }
    __syncthreads();
    if (tid < 64) {
        const float s = red_s[tid][0] + red_s[tid][1] + red_s[tid][2] + red_s[tid][3];
        const float q = red_q[tid][0] + red_q[tid][1] + red_q[tid][2] + red_q[tid][3];
        const float mean = s * (1.f / 256.f);
        const float var  = q * (1.f / 256.f) - mean * mean;
        ln_m[tid] = mean;
        ln_r[tid] = rsqrtf(var + 1e-5f);
    }
    __syncthreads();

    float gv[4], bev[4];
    #pragma unroll
    for (int nf = 0; nf < 4; ++nf) {
        const int col = wv * 64 + nf * 16 + ln15;
        gv[nf]  = args.g[pred][col];
        bev[nf] = args.be[pred][col];
    }

    if (!LIN) {
        bf16* ob = h1out + (size_t)pred * H1SZ + ((size_t)(b * SS + s0)) * HH;
        #pragma unroll
        for (int mf = 0; mf < 4; ++mf) {
            #pragma unroll
            for (int i = 0; i < 4; ++i) {
                const int row = 16 * mf + (lane >> 4) * 4 + i;
                const float mean = ln_m[row], rs = ln_r[row];
                #pragma unroll
                for (int nf = 0; nf < 4; ++nf) {
                    const float o = (acc[mf][nf][i] - mean) * rs * gv[nf] + bev[nf];
                    ob[(size_t)row * HH + wv * 64 + nf * 16 + ln15] = (bf16)o;
                }
            }
        }
    } else {
        float lwv[4];
        #pragma unroll
        for (int nf = 0; nf < 4; ++nf) lwv[nf] = args.lw[pred][wv * 64 + nf * 16 + ln15];
        const float lb0 = args.lb[pred][0];
        #pragma unroll
        for (int mf = 0; mf < 4; ++mf) {
            #pragma unroll
            for (int i = 0; i < 4; ++i) {
                const int row = 16 * mf + (lane >> 4) * 4 + i;
                const float mean = ln_m[row], rs = ln_r[row];
                float t = 0.f;
                #pragma unroll
                for (int nf = 0; nf < 4; ++nf)
                    t += ((acc[mf][nf][i] - mean) * rs * gv[nf] + bev[nf]) * lwv[nf];
                #pragma unroll
                for (int off = 1; off < 16; off <<= 1) t += __shfl_xor(t, off);
                if (ln15 == 0) red_s[row][wv] = t;
            }
        }
        __syncthreads();
        if (tid < 64) {
            const int gr = b * SS + s0 + tid;
            const float dv = red_s[tid][0] + red_s[tid][1] + red_s[tid][2] + red_s[tid][3] + lb0;
            args.out[pred][gr] = mask[gr] ? 0.f : dv;
        }
    }
}

// ------- duration cumsum + d_rounded + mel_len + scatter expansion index -----
__global__ void dur_kernel(const int* __restrict__ dur, int* __restrict__ idxb,
                           int* __restrict__ mli,
                           float* __restrict__ drnd, float* __restrict__ mlen) {
    __shared__ int sb[SS];
    const int b = blockIdx.x, t = threadIdx.x;
    const int v = dur[b * SS + t];
    drnd[b * SS + t] = (float)v;
    sb[t] = v;
    __syncthreads();
    for (int off = 1; off < SS; off <<= 1) {
        const int add = (t >= off) ? sb[t - off] : 0;
        __syncthreads();
        sb[t] += add;
        __syncthreads();
    }
    const int hi = sb[t];
    const int lo = hi - v;
    for (int j = lo; j < hi; ++j) idxb[b * TT + j] = t;   // disjoint ranges
    if (t == SS - 1) { mlen[b] = (float)hi; mli[b] = hi; }
}

// ---------------- length regulator (precomputed idx, grid-stride) ------------
__global__ __launch_bounds__(256) void gather_kernel(
    const float* __restrict__ x,
    const float* __restrict__ ptab, const float* __restrict__ pt,
    const float* __restrict__ etab, const float* __restrict__ et,
    const int* __restrict__ idxb, const int* __restrict__ mli,
    float* __restrict__ mel)
{
    const int lane = threadIdx.x & 63;
    for (int row = blockIdx.x * 4 + (threadIdx.x >> 6); row < BB * TT; row += 4096 * 4) {
        const int b = row >> 11;
        const int t = row & (TT - 1);
        float4 v = make_float4(0.f, 0.f, 0.f, 0.f);
        if (t < mli[b]) {
            const int idx = idxb[row];
            const size_t src = ((size_t)b * SS + idx) * HH + lane * 4;
            v = *(const float4*)(x + src);
            const int pb = bucket256(pt[b * SS + idx]);
            const int eb = bucket256(et[b * SS + idx]);
            const float4 pv = *(const float4*)(ptab + (size_t)pb * HH + lane * 4);
            const float4 ev = *(const float4*)(etab + (size_t)eb * HH + lane * 4);
            v.x += pv.x + ev.x; v.y += pv.y + ev.y; v.z += pv.z + ev.z; v.w += pv.w + ev.w;
        }
        *(float4*)(mel + (size_t)row * HH + lane * 4) = v;
    }
}

// ---------------- launch -----------------------------------------------------
extern "C" void kernel_launch(void* const* d_in, const int* in_sizes, int n_in,
                              void* d_out, int out_size, void* d_ws, size_t ws_size,
                              hipStream_t stream) {
    (void)in_sizes; (void)n_in; (void)out_size; (void)ws_size;

    const float*   x      = (const float*)d_in[0];
    const float*   pitch  = (const float*)d_in[1];
    const float*   energy = (const float*)d_in[2];
    const uint8_t* mask   = (const uint8_t*)d_in[3];
    const int*     dur    = (const int*)d_in[4];
    const float*   ptab   = (const float*)d_in[36];
    const float*   etab   = (const float*)d_in[37];

    float* out = (float*)d_out;
    const size_t N_MEL = (size_t)BB * TT * HH;
    float* out_p  = out + N_MEL;
    float* out_e  = out_p + (size_t)BB * SS;
    float* out_ld = out_e + (size_t)BB * SS;
    float* out_dr = out_ld + (size_t)BB * SS;
    float* out_ml = out_dr + (size_t)BB * SS;

    // ws: packed weights (2.36 MB) | idxb (B*T int, 512 KB) | mli (64 int)
    bf16* wpk  = (bf16*)d_ws;
    int*  idxb = (int*)(wpk + 6 * WSZ);
    int*  mli  = idxb + (size_t)BB * TT;

    // scratch in the mel output region (134 MB, fully rewritten by gather):
    // h1 (3x16.8MB) | x1 (16.8MB) | x2 (16.8MB)
    bf16* h1 = (bf16*)out;
    bf16* x1 = h1 + 3 * H1SZ;
    bf16* x2 = x1 + H1SZ;

    wt_pack<<<18, 256, 0, stream>>>(
        (const float*)d_in[6],  (const float*)d_in[10],
        (const float*)d_in[16], (const float*)d_in[20],
        (const float*)d_in[26], (const float*)d_in[30],
        wpk);
    xcvt_kernel<<<(BB * SS) / 8, 256, 0, stream>>>(x, pitch, ptab, x1, x2);
    dur_kernel<<<BB, SS, 0, stream>>>(dur, idxb, mli, out_dr, out_ml);

    Args3 a1 = {
        {(const float*)d_in[7],  (const float*)d_in[17], (const float*)d_in[27]},
        {(const float*)d_in[8],  (const float*)d_in[18], (const float*)d_in[28]},
        {(const float*)d_in[9],  (const float*)d_in[19], (const float*)d_in[29]},
        {nullptr, nullptr, nullptr}, {nullptr, nullptr, nullptr},
        {nullptr, nullptr, nullptr}
    };
    Args3 a2 = {
        {(const float*)d_in[11], (const float*)d_in[21], (const float*)d_in[31]},
        {(const float*)d_in[12], (const float*)d_in[22], (const float*)d_in[32]},
        {(const float*)d_in[13], (const float*)d_in[23], (const float*)d_in[33]},
        {(const float*)d_in[14], (const float*)d_in[24], (const float*)d_in[34]},
        {(const float*)d_in[15], (const float*)d_in[25], (const float*)d_in[35]},
        {out_ld, out_p, out_e}
    };

    conv_all<false><<<3 * 512, 256, 0, stream>>>(x1, x2, wpk, a1, h1, nullptr);
    conv_all<true ><<<3 * 512, 256, 0, stream>>>(h1, nullptr, wpk, a2, nullptr, mask);

    gather_kernel<<<4096, 256, 0, stream>>>(x, ptab, pitch, etab, energy, idxb, mli, out);
}

// Round 8
// 167.342 us; speedup vs baseline: 1.2027x; 1.2027x over previous
//
#include <hip/hip_runtime.h>
#include <cstdint>
#include <cstddef>

// VarianceAdaptor — R8: conv1+conv2 FUSED in one kernel. Stage1 computes 80
// rows (covers 66-row h halo), LN'd h-tile goes to LDS (reuses X region),
// stage2 reads h from LDS. Kills the h1 HBM round-trip and one dispatch.
// B=64, S=512, T=2048, H=F=256, K=3, NBINS=256.

#define HH 256
#define SS 512
#define BB 64
#define TT 2048

typedef __bf16 bf16;
typedef __attribute__((ext_vector_type(8))) __bf16 bf16x8;
typedef __attribute__((ext_vector_type(4))) float f32x4;

static constexpr size_t WSZ  = (size_t)3 * HH * HH;   // elems per conv weight
static constexpr size_t H1SZ = (size_t)BB * SS * HH;  // elems per x1/x2 buffer

// swizzled halfword index into a [rows][256] bf16 LDS tile (row stride 512B).
__device__ __forceinline__ int swz(int r, int c) { return (r * HH + c) ^ ((r & 7) << 3); }

__device__ __forceinline__ void gload16(const void* g, void* l) {
    __builtin_amdgcn_global_load_lds(
        (const __attribute__((address_space(1))) unsigned int*)g,
        (__attribute__((address_space(3))) unsigned int*)l, 16, 0, 0);
}

// ---------------- bucket (searchsorted over jnp.linspace(-2,2,255) edges) ----
__device__ __forceinline__ float edge_val(int j) {
    const float step = 4.0f / 254.0f;
    if (j == 254) return 2.0f;
    return __fadd_rn(-2.0f, __fmul_rn((float)j, step));
}
__device__ __forceinline__ int bucket256(float v) {
    int lo = 0, hi = 255;
    while (lo < hi) {
        int mid = (lo + hi) >> 1;
        if (edge_val(mid) < v) lo = mid + 1; else hi = mid;
    }
    return lo;
}

// ------------- weight pack: w[k][c][f] f32 -> wp[k][fb][kcb][lane][8] bf16 ---
// B-frag for mfma_16x16x32: lane l holds B[col = fb*16 + (l&15)]
//                                  [c   = kcb*32 + (l>>4)*8 + j], j=0..7
__global__ void wt_pack(const float* __restrict__ w0, const float* __restrict__ w1,
                        const float* __restrict__ w2, const float* __restrict__ w3,
                        const float* __restrict__ w4, const float* __restrict__ w5,
                        bf16* __restrict__ wp) {
    const int cv = blockIdx.x / 3, k = blockIdx.x % 3;
    const float* wsel[6] = {w0, w1, w2, w3, w4, w5};
    const float* wk = wsel[cv] + (size_t)k * HH * HH;   // [c][f]
    bf16* o = wp + ((size_t)(cv * 3 + k)) * HH * HH;
    for (int fb = 0; fb < 16; ++fb) {
        #pragma unroll
        for (int h = 0; h < 2; ++h) {
            const int idx  = threadIdx.x + 256 * h;     // 0..511
            const int kcb  = idx >> 6, lane = idx & 63;
            const int f    = fb * 16 + (lane & 15);
            const int c0   = kcb * 32 + (lane >> 4) * 8;
            bf16x8 v;
            #pragma unroll
            for (int j = 0; j < 8; ++j) v[j] = (bf16)wk[(size_t)(c0 + j) * HH + f];
            *(bf16x8*)(o + (((size_t)fb * 8 + kcb) * 64 + lane) * 8) = v;
        }
    }
}

// ------------- x convert: x1 = bf16(x), x2 = bf16(x + p_table[bucket]) -------
__global__ __launch_bounds__(256) void xcvt_kernel(
    const float* __restrict__ x, const float* __restrict__ pt,
    const float* __restrict__ ptab,
    bf16* __restrict__ x1, bf16* __restrict__ x2)
{
    const int row = blockIdx.x * 8 + (threadIdx.x >> 5);   // 0 .. B*S-1
    const int c   = (threadIdx.x & 31) * 8;
    const int pb  = bucket256(pt[row]);
    const float4 v0 = *(const float4*)(x + (size_t)row * HH + c);
    const float4 v1 = *(const float4*)(x + (size_t)row * HH + c + 4);
    const float4 t0 = *(const float4*)(ptab + (size_t)pb * HH + c);
    const float4 t1 = *(const float4*)(ptab + (size_t)pb * HH + c + 4);
    bf16x8 a, b2;
    a[0] = (bf16)v0.x; a[1] = (bf16)v0.y; a[2] = (bf16)v0.z; a[3] = (bf16)v0.w;
    a[4] = (bf16)v1.x; a[5] = (bf16)v1.y; a[6] = (bf16)v1.z; a[7] = (bf16)v1.w;
    b2[0] = (bf16)(v0.x + t0.x); b2[1] = (bf16)(v0.y + t0.y);
    b2[2] = (bf16)(v0.z + t0.z); b2[3] = (bf16)(v0.w + t0.w);
    b2[4] = (bf16)(v1.x + t1.x); b2[5] = (bf16)(v1.y + t1.y);
    b2[6] = (bf16)(v1.z + t1.z); b2[7] = (bf16)(v1.w + t1.w);
    *(bf16x8*)(x1 + (size_t)row * HH + c) = a;
    *(bf16x8*)(x2 + (size_t)row * HH + c) = b2;
}

// ---------------- fused conv1+conv2 (3 predictors in one grid) ---------------
struct Args3 {
    const float* bias[3];
    const float* g[3];
    const float* be[3];
    const float* lw[3];
    const float* lb[3];
    float*       out[3];
};

// grid = 3*512; 256 threads = 4 waves; wave wv owns cols [64wv, 64wv+64).
// X LDS tile: 84 rows (row 0 = seq s0-9). Stage1 computes 80 rel rows
// (rel row r = seq s0-8+r, frag rows 16mf+ln15). h LDS tile overwrites X:
// 66 rows (row 0 = seq s0-1). Stage2 computes the block's 64 output rows.
__global__ __launch_bounds__(256, 3) void conv_fused(
    const bf16* __restrict__ x1,      // (B,S,256) bf16
    const bf16* __restrict__ x2,      // (B,S,256) bf16 (x + p_emb), pred 2
    const bf16* __restrict__ wpk,     // packed weights, 6 convs
    Args3 a1, Args3 a2,
    const uint8_t* __restrict__ mask)
{
    __shared__ alignas(16) bf16 tile[84 * HH];          // 43KB: X, then h
    __shared__ float red_s[80][4], red_q[80][4];
    __shared__ float ln_m[80], ln_r[80];

    const int tid    = threadIdx.x;
    const int pred   = blockIdx.x >> 9;
    const int within = blockIdx.x & 511;
    const int b      = within >> 3;
    const int s0     = (within & 7) * 64;

    const int lane = tid & 63;
    const int wv   = tid >> 6;

    const bf16* inb = (pred == 2 ? x2 : x1) + (size_t)b * SS * HH;
    const bf16* wt1 = wpk + (size_t)(pred * 2) * WSZ;
    const bf16* wt2 = wt1 + WSZ;

    // ---- stage X tile: 84 rows, pre-swizzled global src, linear LDS dest ----
    for (int c = wv; c < 42; c += 4) {
        const int rrow = 2 * c + (lane >> 5);           // 0..83
        const int s    = s0 - 9 + rrow;
        const int sc   = min(max(s, 0), SS - 1);
        const char* src = (const char*)inb + (size_t)sc * 512
                        + (((lane & 31) * 16) ^ ((rrow & 7) << 4));
        gload16(src, (char*)tile + (size_t)c * 1024);
    }
    __syncthreads();
    // zero rows whose seq index is out of [0,S)
    if (s0 == 0) {                                      // rows 0..8 (seq -9..-1)
        for (int idx = tid; idx < 9 * 32; idx += 256) {
            const int r = idx >> 5, o = idx & 31;
            ((uint4*)tile)[r * 32 + o] = make_uint4(0u, 0u, 0u, 0u);
        }
    }
    if (s0 == SS - 64) {                                // rows 73..83 (seq >= S)
        for (int idx = tid; idx < 11 * 32; idx += 256) {
            const int r = 73 + (idx >> 5), o = idx & 31;
            ((uint4*)tile)[r * 32 + o] = make_uint4(0u, 0u, 0u, 0u);
        }
    }
    __syncthreads();

    const int ln15 = lane & 15;
    const int g8   = (lane >> 4) << 3;
    const int hi4  = (lane >> 4) * 4;

    // ================= stage 1: conv1 over 80 rel rows =================
    f32x4 acc1[5][4];
    #pragma unroll
    for (int nf = 0; nf < 4; ++nf) {
        const float bv = a1.bias[pred][wv * 64 + nf * 16 + ln15];
        #pragma unroll
        for (int mf = 0; mf < 5; ++mf) acc1[mf][nf] = f32x4{bv, bv, bv, bv};
    }

    #pragma unroll 2
    for (int t = 0; t < 24; ++t) {
        const int k = t >> 3, kcb = t & 7;
        const int kc = kcb << 5;
        bf16x8 a[5], bb[4];
        #pragma unroll
        for (int mf = 0; mf < 5; ++mf)   // X LDS row = rel row + k
            a[mf] = *(const bf16x8*)&tile[swz(16 * mf + ln15 + k, kc + g8)];
        const bf16* bp = wt1 + ((((size_t)k * 16 + wv * 4) * 8 + kcb) << 9)
                       + (size_t)lane * 8;
        #pragma unroll
        for (int nf = 0; nf < 4; ++nf)
            bb[nf] = *(const bf16x8*)(bp + ((size_t)nf << 12));
        #pragma unroll
        for (int mf = 0; mf < 5; ++mf)
            #pragma unroll
            for (int nf = 0; nf < 4; ++nf)
                acc1[mf][nf] = __builtin_amdgcn_mfma_f32_16x16x32_bf16(
                    a[mf], bb[nf], acc1[mf][nf], 0, 0, 0);
    }

    // ReLU + LN partials over 80 rows
    #pragma unroll
    for (int mf = 0; mf < 5; ++mf) {
        #pragma unroll
        for (int i = 0; i < 4; ++i) {
            #pragma unroll
            for (int nf = 0; nf < 4; ++nf)
                acc1[mf][nf][i] = fmaxf(acc1[mf][nf][i], 0.f);
            float s = acc1[mf][0][i] + acc1[mf][1][i] + acc1[mf][2][i] + acc1[mf][3][i];
            float q = acc1[mf][0][i] * acc1[mf][0][i] + acc1[mf][1][i] * acc1[mf][1][i]
                    + acc1[mf][2][i] * acc1[mf][2][i] + acc1[mf][3][i] * acc1[mf][3][i];
            #pragma unroll
            for (int off = 1; off < 16; off <<= 1) {
                s += __shfl_xor(s, off);
                q += __shfl_xor(q, off);
            }
            if (ln15 == 0) {
                const int rr = 16 * mf + hi4 + i;
                red_s[rr][wv] = s;
                red_q[rr][wv] = q;
            }
        }
    }
    __syncthreads();
    if (tid < 80) {
        const float s = red_s[tid][0] + red_s[tid][1] + red_s[tid][2] + red_s[tid][3];
        const float q = red_q[tid][0] + red_q[tid][1] + red_q[tid][2] + red_q[tid][3];
        const float mean = s * (1.f / 256.f);
        const float var  = q * (1.f / 256.f) - mean * mean;
        ln_m[tid] = mean;
        ln_r[tid] = rsqrtf(var + 1e-5f);
    }
    __syncthreads();    // also: all waves done reading X -> tile reusable

    // ---- write h rows (rel rows 7..72 -> h LDS rows 0..65), swizzled ----
    {
        float gv1[4], bev1[4];
        #pragma unroll
        for (int nf = 0; nf < 4; ++nf) {
            const int col = wv * 64 + nf * 16 + ln15;
            gv1[nf]  = a1.g[pred][col];
            bev1[nf] = a1.be[pred][col];
        }
        #pragma unroll
        for (int mf = 0; mf < 5; ++mf) {
            #pragma unroll
            for (int i = 0; i < 4; ++i) {
                const int rr = 16 * mf + hi4 + i;
                const int hr = rr - 7;
                if (hr >= 0 && hr <= 65) {
                    const float mean = ln_m[rr], rs = ln_r[rr];
                    #pragma unroll
                    for (int nf = 0; nf < 4; ++nf) {
                        const float o = (acc1[mf][nf][i] - mean) * rs * gv1[nf] + bev1[nf];
                        tile[swz(hr, wv * 64 + nf * 16 + ln15)] = (bf16)o;
                    }
                }
            }
        }
    }
    __syncthreads();
    // zero h halo rows at batch edges (conv2 zero-padding)
    if (tid < 64) {
        if (s0 == 0)       *(uint2*)&tile[tid * 4]           = make_uint2(0u, 0u);
        if (s0 == SS - 64) *(uint2*)&tile[65 * HH + tid * 4] = make_uint2(0u, 0u);
    }
    __syncthreads();

    // ================= stage 2: conv2 + LN + linear =================
    f32x4 acc2[4][4];
    #pragma unroll
    for (int nf = 0; nf < 4; ++nf) {
        const float bv = a2.bias[pred][wv * 64 + nf * 16 + ln15];
        #pragma unroll
        for (int mf = 0; mf < 4; ++mf) acc2[mf][nf] = f32x4{bv, bv, bv, bv};
    }

    #pragma unroll 2
    for (int t = 0; t < 24; ++t) {
        const int k = t >> 3, kcb = t & 7;
        const int kc = kcb << 5;
        bf16x8 a[4], bb[4];
        #pragma unroll
        for (int mf = 0; mf < 4; ++mf)   // h LDS row = out row + k (row0 = seq s0-1)
            a[mf] = *(const bf16x8*)&tile[swz(16 * mf + ln15 + k, kc + g8)];
        const bf16* bp = wt2 + ((((size_t)k * 16 + wv * 4) * 8 + kcb) << 9)
                       + (size_t)lane * 8;
        #pragma unroll
        for (int nf = 0; nf < 4; ++nf)
            bb[nf] = *(const bf16x8*)(bp + ((size_t)nf << 12));
        #pragma unroll
        for (int mf = 0; mf < 4; ++mf)
            #pragma unroll
            for (int nf = 0; nf < 4; ++nf)
                acc2[mf][nf] = __builtin_amdgcn_mfma_f32_16x16x32_bf16(
                    a[mf], bb[nf], acc2[mf][nf], 0, 0, 0);
    }

    // ReLU + LN partials over 64 rows
    #pragma unroll
    for (int mf = 0; mf < 4; ++mf) {
        #pragma unroll
        for (int i = 0; i < 4; ++i) {
            #pragma unroll
            for (int nf = 0; nf < 4; ++nf)
                acc2[mf][nf][i] = fmaxf(acc2[mf][nf][i], 0.f);
            float s = acc2[mf][0][i] + acc2[mf][1][i] + acc2[mf][2][i] + acc2[mf][3][i];
            float q = acc2[mf][0][i] * acc2[mf][0][i] + acc2[mf][1][i] * acc2[mf][1][i]
                    + acc2[mf][2][i] * acc2[mf][2][i] + acc2[mf][3][i] * acc2[mf][3][i];
            #pragma unroll
            for (int off = 1; off < 16; off <<= 1) {
                s += __shfl_xor(s, off);
                q += __shfl_xor(q, off);
            }
            if (ln15 == 0) {
                const int rr = 16 * mf + hi4 + i;
                red_s[rr][wv] = s;
                red_q[rr][wv] = q;
            }
        }
    }
    __syncthreads();
    if (tid < 64) {
        const float s = red_s[tid][0] + red_s[tid][1] + red_s[tid][2] + red_s[tid][3];
        const float q = red_q[tid][0] + red_q[tid][1] + red_q[tid][2] + red_q[tid][3];
        const float mean = s * (1.f / 256.f);
        const float var  = q * (1.f / 256.f) - mean * mean;
        ln_m[tid] = mean;
        ln_r[tid] = rsqrtf(var + 1e-5f);
    }
    __syncthreads();

    {
        float gv2[4], bev2[4], lwv[4];
        #pragma unroll
        for (int nf = 0; nf < 4; ++nf) {
            const int col = wv * 64 + nf * 16 + ln15;
            gv2[nf]  = a2.g[pred][col];
            bev2[nf] = a2.be[pred][col];
            lwv[nf]  = a2.lw[pred][col];
        }
        const float lb0 = a2.lb[pred][0];
        #pragma unroll
        for (int mf = 0; mf < 4; ++mf) {
            #pragma unroll
            for (int i = 0; i < 4; ++i) {
                const int row = 16 * mf + hi4 + i;
                const float mean = ln_m[row], rs = ln_r[row];
                float t = 0.f;
                #pragma unroll
                for (int nf = 0; nf < 4; ++nf)
                    t += ((acc2[mf][nf][i] - mean) * rs * gv2[nf] + bev2[nf]) * lwv[nf];
                #pragma unroll
                for (int off = 1; off < 16; off <<= 1) t += __shfl_xor(t, off);
                if (ln15 == 0) red_s[row][wv] = t;
            }
        }
        __syncthreads();
        if (tid < 64) {
            const int gr = b * SS + s0 + tid;
            const float dv = red_s[tid][0] + red_s[tid][1] + red_s[tid][2] + red_s[tid][3] + lb0;
            a2.out[pred][gr] = mask[gr] ? 0.f : dv;
        }
    }
}

// ------- duration cumsum + d_rounded + mel_len + scatter expansion index -----
__global__ void dur_kernel(const int* __restrict__ dur, int* __restrict__ idxb,
                           int* __restrict__ mli,
                           float* __restrict__ drnd, float* __restrict__ mlen) {
    __shared__ int sb[SS];
    const int b = blockIdx.x, t = threadIdx.x;
    const int v = dur[b * SS + t];
    drnd[b * SS + t] = (float)v;
    sb[t] = v;
    __syncthreads();
    for (int off = 1; off < SS; off <<= 1) {
        const int add = (t >= off) ? sb[t - off] : 0;
        __syncthreads();
        sb[t] += add;
        __syncthreads();
    }
    const int hi = sb[t];
    const int lo = hi - v;
    for (int j = lo; j < hi; ++j) idxb[b * TT + j] = t;   // disjoint ranges
    if (t == SS - 1) { mlen[b] = (float)hi; mli[b] = hi; }
}

// ---------------- length regulator (precomputed idx, grid-stride) ------------
__global__ __launch_bounds__(256) void gather_kernel(
    const float* __restrict__ x,
    const float* __restrict__ ptab, const float* __restrict__ pt,
    const float* __restrict__ etab, const float* __restrict__ et,
    const int* __restrict__ idxb, const int* __restrict__ mli,
    float* __restrict__ mel)
{
    const int lane = threadIdx.x & 63;
    for (int row = blockIdx.x * 4 + (threadIdx.x >> 6); row < BB * TT; row += 4096 * 4) {
        const int b = row >> 11;
        const int t = row & (TT - 1);
        float4 v = make_float4(0.f, 0.f, 0.f, 0.f);
        if (t < mli[b]) {
            const int idx = idxb[row];
            const size_t src = ((size_t)b * SS + idx) * HH + lane * 4;
            v = *(const float4*)(x + src);
            const int pb = bucket256(pt[b * SS + idx]);
            const int eb = bucket256(et[b * SS + idx]);
            const float4 pv = *(const float4*)(ptab + (size_t)pb * HH + lane * 4);
            const float4 ev = *(const float4*)(etab + (size_t)eb * HH + lane * 4);
            v.x += pv.x + ev.x; v.y += pv.y + ev.y; v.z += pv.z + ev.z; v.w += pv.w + ev.w;
        }
        *(float4*)(mel + (size_t)row * HH + lane * 4) = v;
    }
}

// ---------------- launch -----------------------------------------------------
extern "C" void kernel_launch(void* const* d_in, const int* in_sizes, int n_in,
                              void* d_out, int out_size, void* d_ws, size_t ws_size,
                              hipStream_t stream) {
    (void)in_sizes; (void)n_in; (void)out_size; (void)ws_size;

    const float*   x      = (const float*)d_in[0];
    const float*   pitch  = (const float*)d_in[1];
    const float*   energy = (const float*)d_in[2];
    const uint8_t* mask   = (const uint8_t*)d_in[3];
    const int*     dur    = (const int*)d_in[4];
    const float*   ptab   = (const float*)d_in[36];
    const float*   etab   = (const float*)d_in[37];

    float* out = (float*)d_out;
    const size_t N_MEL = (size_t)BB * TT * HH;
    float* out_p  = out + N_MEL;
    float* out_e  = out_p + (size_t)BB * SS;
    float* out_ld = out_e + (size_t)BB * SS;
    float* out_dr = out_ld + (size_t)BB * SS;
    float* out_ml = out_dr + (size_t)BB * SS;

    // ws: packed weights (2.36 MB) | idxb (B*T int, 512 KB) | mli (64 int)
    bf16* wpk  = (bf16*)d_ws;
    int*  idxb = (int*)(wpk + 6 * WSZ);
    int*  mli  = idxb + (size_t)BB * TT;

    // scratch in the mel output region (134 MB, fully rewritten by gather):
    // x1 (16.8MB) | x2 (16.8MB)
    bf16* x1 = (bf16*)out;
    bf16* x2 = x1 + H1SZ;

    wt_pack<<<18, 256, 0, stream>>>(
        (const float*)d_in[6],  (const float*)d_in[10],
        (const float*)d_in[16], (const float*)d_in[20],
        (const float*)d_in[26], (const float*)d_in[30],
        wpk);
    xcvt_kernel<<<(BB * SS) / 8, 256, 0, stream>>>(x, pitch, ptab, x1, x2);
    dur_kernel<<<BB, SS, 0, stream>>>(dur, idxb, mli, out_dr, out_ml);

    Args3 a1 = {
        {(const float*)d_in[7],  (const float*)d_in[17], (const float*)d_in[27]},
        {(const float*)d_in[8],  (const float*)d_in[18], (const float*)d_in[28]},
        {(const float*)d_in[9],  (const float*)d_in[19], (const float*)d_in[29]},
        {nullptr, nullptr, nullptr}, {nullptr, nullptr, nullptr},
        {nullptr, nullptr, nullptr}
    };
    Args3 a2 = {
        {(const float*)d_in[11], (const float*)d_in[21], (const float*)d_in[31]},
        {(const float*)d_in[12], (const float*)d_in[22], (const float*)d_in[32]},
        {(const float*)d_in[13], (const float*)d_in[23], (const float*)d_in[33]},
        {(const float*)d_in[14], (const float*)d_in[24], (const float*)d_in[34]},
        {(const float*)d_in[15], (const float*)d_in[25], (const float*)d_in[35]},
        {out_ld, out_p, out_e}
    };

    conv_fused<<<3 * 512, 256, 0, stream>>>(x1, x2, wpk, a1, a2, mask);

    gather_kernel<<<4096, 256, 0, stream>>>(x, ptab, pitch, etab, energy, idxb, mli, out);
}

// Round 9
// 152.119 us; speedup vs baseline: 1.3231x; 1.1001x over previous
//
#include <hip/hip_runtime.h>
#include <cstdint>
#include <cstddef>

// VarianceAdaptor — R9: swapped-operand MFMA (D[f][s] = W^T x^T) so the
// channel axis is register-local: LN = in-reg sum + 2 shuffles, h-write =
// packed ds_write_b64, linear = in-reg dot. Same packed weights, same staging.
// B=64, S=512, T=2048, H=F=256, K=3, NBINS=256.

#define HH 256
#define SS 512
#define BB 64
#define TT 2048

typedef __bf16 bf16;
typedef __attribute__((ext_vector_type(8))) __bf16 bf16x8;
typedef __attribute__((ext_vector_type(4))) __bf16 bf16x4;
typedef __attribute__((ext_vector_type(4))) float f32x4;

static constexpr size_t WSZ  = (size_t)3 * HH * HH;   // elems per conv weight
static constexpr size_t H1SZ = (size_t)BB * SS * HH;  // elems per x1/x2 buffer

// swizzled halfword index into a [rows][256] bf16 LDS tile (row stride 512B).
__device__ __forceinline__ int swz(int r, int c) { return (r * HH + c) ^ ((r & 7) << 3); }

__device__ __forceinline__ void gload16(const void* g, void* l) {
    __builtin_amdgcn_global_load_lds(
        (const __attribute__((address_space(1))) unsigned int*)g,
        (__attribute__((address_space(3))) unsigned int*)l, 16, 0, 0);
}

// ---------------- bucket (searchsorted over jnp.linspace(-2,2,255) edges) ----
__device__ __forceinline__ float edge_val(int j) {
    const float step = 4.0f / 254.0f;
    if (j == 254) return 2.0f;
    return __fadd_rn(-2.0f, __fmul_rn((float)j, step));
}
__device__ __forceinline__ int bucket256(float v) {
    int lo = 0, hi = 255;
    while (lo < hi) {
        int mid = (lo + hi) >> 1;
        if (edge_val(mid) < v) lo = mid + 1; else hi = mid;
    }
    return lo;
}

// ------------- weight pack: w[k][c][f] f32 -> wp[k][fb][kcb][lane][8] bf16 ---
// frag: lane l holds [dim16 = fb*16 + (l&15)][k = kcb*32 + (l>>4)*8 + j]
// (works as either A- or B-operand of mfma_16x16x32 — same per-lane layout)
__global__ void wt_pack(const float* __restrict__ w0, const float* __restrict__ w1,
                        const float* __restrict__ w2, const float* __restrict__ w3,
                        const float* __restrict__ w4, const float* __restrict__ w5,
                        bf16* __restrict__ wp) {
    const int cv = blockIdx.x / 3, k = blockIdx.x % 3;
    const float* wsel[6] = {w0, w1, w2, w3, w4, w5};
    const float* wk = wsel[cv] + (size_t)k * HH * HH;   // [c][f]
    bf16* o = wp + ((size_t)(cv * 3 + k)) * HH * HH;
    for (int fb = 0; fb < 16; ++fb) {
        #pragma unroll
        for (int h = 0; h < 2; ++h) {
            const int idx  = threadIdx.x + 256 * h;     // 0..511
            const int kcb  = idx >> 6, lane = idx & 63;
            const int f    = fb * 16 + (lane & 15);
            const int c0   = kcb * 32 + (lane >> 4) * 8;
            bf16x8 v;
            #pragma unroll
            for (int j = 0; j < 8; ++j) v[j] = (bf16)wk[(size_t)(c0 + j) * HH + f];
            *(bf16x8*)(o + (((size_t)fb * 8 + kcb) * 64 + lane) * 8) = v;
        }
    }
}

// ------------- x convert: x1 = bf16(x), x2 = bf16(x + p_table[bucket]) -------
__global__ __launch_bounds__(256) void xcvt_kernel(
    const float* __restrict__ x, const float* __restrict__ pt,
    const float* __restrict__ ptab,
    bf16* __restrict__ x1, bf16* __restrict__ x2)
{
    const int row = blockIdx.x * 8 + (threadIdx.x >> 5);   // 0 .. B*S-1
    const int c   = (threadIdx.x & 31) * 8;
    const int pb  = bucket256(pt[row]);
    const float4 v0 = *(const float4*)(x + (size_t)row * HH + c);
    const float4 v1 = *(const float4*)(x + (size_t)row * HH + c + 4);
    const float4 t0 = *(const float4*)(ptab + (size_t)pb * HH + c);
    const float4 t1 = *(const float4*)(ptab + (size_t)pb * HH + c + 4);
    bf16x8 a, b2;
    a[0] = (bf16)v0.x; a[1] = (bf16)v0.y; a[2] = (bf16)v0.z; a[3] = (bf16)v0.w;
    a[4] = (bf16)v1.x; a[5] = (bf16)v1.y; a[6] = (bf16)v1.z; a[7] = (bf16)v1.w;
    b2[0] = (bf16)(v0.x + t0.x); b2[1] = (bf16)(v0.y + t0.y);
    b2[2] = (bf16)(v0.z + t0.z); b2[3] = (bf16)(v0.w + t0.w);
    b2[4] = (bf16)(v1.x + t1.x); b2[5] = (bf16)(v1.y + t1.y);
    b2[6] = (bf16)(v1.z + t1.z); b2[7] = (bf16)(v1.w + t1.w);
    *(bf16x8*)(x1 + (size_t)row * HH + c) = a;
    *(bf16x8*)(x2 + (size_t)row * HH + c) = b2;
}

// ---------------- fused conv1+conv2, swapped-operand MFMA --------------------
struct Args3 {
    const float* bias[3];
    const float* g[3];
    const float* be[3];
    const float* lw[3];
    const float* lb[3];
    float*       out[3];
};

// grid = 3*512; 256 threads = 4 waves; wave wv owns f-rows [64wv, 64wv+64).
// X LDS tile: 84 rows, row r = seq s0-9+r. Stage1 output o (=D col index
// 16sf+ln15) = seq s0-8+o, o in [0,80). h rows hr = o-7 in [0,66).
__global__ __launch_bounds__(256, 3) void conv_fused(
    const bf16* __restrict__ x1,      // (B,S,256) bf16
    const bf16* __restrict__ x2,      // (B,S,256) bf16 (x + p_emb), pred 2
    const bf16* __restrict__ wpk,     // packed weights, 6 convs
    Args3 a1, Args3 a2,
    const uint8_t* __restrict__ mask)
{
    __shared__ alignas(16) bf16 tile[84 * HH];          // 43KB: X, then h
    __shared__ float red_s[80][4], red_q[80][4];
    __shared__ float ln_m[80], ln_r[80];

    const int tid    = threadIdx.x;
    const int pred   = blockIdx.x >> 9;
    const int within = blockIdx.x & 511;
    const int b      = within >> 3;
    const int s0     = (within & 7) * 64;

    const int lane = tid & 63;
    const int wv   = tid >> 6;

    const bf16* inb = (pred == 2 ? x2 : x1) + (size_t)b * SS * HH;
    const bf16* wt1 = wpk + (size_t)(pred * 2) * WSZ;
    const bf16* wt2 = wt1 + WSZ;

    // ---- stage X tile: 84 rows, pre-swizzled global src, linear LDS dest ----
    for (int c = wv; c < 42; c += 4) {
        const int rrow = 2 * c + (lane >> 5);           // 0..83
        const int s    = s0 - 9 + rrow;
        const int sc   = min(max(s, 0), SS - 1);
        const char* src = (const char*)inb + (size_t)sc * 512
                        + (((lane & 31) * 16) ^ ((rrow & 7) << 4));
        gload16(src, (char*)tile + (size_t)c * 1024);
    }
    __syncthreads();
    // zero rows whose seq index is out of [0,S)
    if (s0 == 0) {                                      // rows 0..8 (seq -9..-1)
        for (int idx = tid; idx < 9 * 32; idx += 256) {
            const int r = idx >> 5, o = idx & 31;
            ((uint4*)tile)[r * 32 + o] = make_uint4(0u, 0u, 0u, 0u);
        }
    }
    if (s0 == SS - 64) {                                // rows 73..83 (seq >= S)
        for (int idx = tid; idx < 11 * 32; idx += 256) {
            const int r = 73 + (idx >> 5), o = idx & 31;
            ((uint4*)tile)[r * 32 + o] = make_uint4(0u, 0u, 0u, 0u);
        }
    }
    __syncthreads();

    const int ln15 = lane & 15;
    const int g8   = (lane >> 4) << 3;
    const int q4   = (lane >> 4) << 2;     // in-frag row quad base

    // ============ stage 1: D1[f1][o], f1-frag mf (4), o-tile sf (5) ==========
    f32x4 acc1[4][5];
    #pragma unroll
    for (int mf = 0; mf < 4; ++mf)
        #pragma unroll
        for (int sf = 0; sf < 5; ++sf) acc1[mf][sf] = f32x4{0.f, 0.f, 0.f, 0.f};

    #pragma unroll 2
    for (int t = 0; t < 24; ++t) {
        const int k = t >> 3, kcb = t & 7;
        const int kc = kcb << 5;
        bf16x8 aw[4], bx[5];
        const bf16* bp = wt1 + ((((size_t)k * 16 + wv * 4) * 8 + kcb) << 9)
                       + (size_t)lane * 8;
        #pragma unroll
        for (int mf = 0; mf < 4; ++mf)
            aw[mf] = *(const bf16x8*)(bp + ((size_t)mf << 12));
        #pragma unroll
        for (int sf = 0; sf < 5; ++sf)      // x row = o + tap k
            bx[sf] = *(const bf16x8*)&tile[swz(16 * sf + ln15 + k, kc + g8)];
        #pragma unroll
        for (int mf = 0; mf < 4; ++mf)
            #pragma unroll
            for (int sf = 0; sf < 5; ++sf)
                acc1[mf][sf] = __builtin_amdgcn_mfma_f32_16x16x32_bf16(
                    aw[mf], bx[sf], acc1[mf][sf], 0, 0, 0);
    }

    // bias + ReLU (bias indexed by f1 = row axis = register axis)
    #pragma unroll
    for (int mf = 0; mf < 4; ++mf)
        #pragma unroll
        for (int i = 0; i < 4; ++i) {
            const float bv = a1.bias[pred][64 * wv + 16 * mf + q4 + i];
            #pragma unroll
            for (int sf = 0; sf < 5; ++sf)
                acc1[mf][sf][i] = fmaxf(acc1[mf][sf][i] + bv, 0.f);
        }

    // LN1 partials: per o, sum over f1 = 16 in-reg values + 2 shuffles
    #pragma unroll
    for (int sf = 0; sf < 5; ++sf) {
        float s = 0.f, q = 0.f;
        #pragma unroll
        for (int mf = 0; mf < 4; ++mf)
            #pragma unroll
            for (int i = 0; i < 4; ++i) {
                const float v = acc1[mf][sf][i];
                s += v; q += v * v;
            }
        s += __shfl_xor(s, 16); s += __shfl_xor(s, 32);
        q += __shfl_xor(q, 16); q += __shfl_xor(q, 32);
        if (lane < 16) { red_s[16 * sf + lane][wv] = s; red_q[16 * sf + lane][wv] = q; }
    }
    __syncthreads();
    if (tid < 80) {
        const float s = red_s[tid][0] + red_s[tid][1] + red_s[tid][2] + red_s[tid][3];
        const float q = red_q[tid][0] + red_q[tid][1] + red_q[tid][2] + red_q[tid][3];
        const float mean = s * (1.f / 256.f);
        const float var  = q * (1.f / 256.f) - mean * mean;
        ln_m[tid] = mean;
        ln_r[tid] = rsqrtf(var + 1e-5f);
    }
    __syncthreads();

    // h-write: packed b64 (4 consecutive f1 at one o), rows hr = o-7 in [0,66)
    {
        float g1v[4][4], be1v[4][4];
        #pragma unroll
        for (int mf = 0; mf < 4; ++mf)
            #pragma unroll
            for (int i = 0; i < 4; ++i) {
                const int f1 = 64 * wv + 16 * mf + q4 + i;
                g1v[mf][i]  = a1.g[pred][f1];
                be1v[mf][i] = a1.be[pred][f1];
            }
        #pragma unroll
        for (int sf = 0; sf < 5; ++sf) {
            const int o  = 16 * sf + ln15;
            const int hr = o - 7;
            const float mean = ln_m[o], rs = ln_r[o];
            const bool ok = (o >= 7 && o <= 72);
            #pragma unroll
            for (int mf = 0; mf < 4; ++mf) {
                bf16x4 hv;
                #pragma unroll
                for (int i = 0; i < 4; ++i)
                    hv[i] = (bf16)((acc1[mf][sf][i] - mean) * rs * g1v[mf][i] + be1v[mf][i]);
                if (ok)
                    *(bf16x4*)&tile[swz(hr, 64 * wv + 16 * mf + q4)] = hv;
            }
        }
    }
    __syncthreads();
    // zero h halo rows at batch edges (row-linear zero covers the swizzle)
    if (tid < 64) {
        if (s0 == 0)       *(uint2*)&tile[tid * 4]           = make_uint2(0u, 0u);
        if (s0 == SS - 64) *(uint2*)&tile[65 * HH + tid * 4] = make_uint2(0u, 0u);
    }
    __syncthreads();

    // ============ stage 2: D2[f2][so], so-tile sf (4) ==========
    f32x4 acc2[4][4];
    #pragma unroll
    for (int mf = 0; mf < 4; ++mf)
        #pragma unroll
        for (int sf = 0; sf < 4; ++sf) acc2[mf][sf] = f32x4{0.f, 0.f, 0.f, 0.f};

    #pragma unroll 2
    for (int t = 0; t < 24; ++t) {
        const int k = t >> 3, kcb = t & 7;
        const int kc = kcb << 5;
        bf16x8 aw[4], bx[4];
        const bf16* bp = wt2 + ((((size_t)k * 16 + wv * 4) * 8 + kcb) << 9)
                       + (size_t)lane * 8;
        #pragma unroll
        for (int mf = 0; mf < 4; ++mf)
            aw[mf] = *(const bf16x8*)(bp + ((size_t)mf << 12));
        #pragma unroll
        for (int sf = 0; sf < 4; ++sf)      // h row = so + tap k
            bx[sf] = *(const bf16x8*)&tile[swz(16 * sf + ln15 + k, kc + g8)];
        #pragma unroll
        for (int mf = 0; mf < 4; ++mf)
            #pragma unroll
            for (int sf = 0; sf < 4; ++sf)
                acc2[mf][sf] = __builtin_amdgcn_mfma_f32_16x16x32_bf16(
                    aw[mf], bx[sf], acc2[mf][sf], 0, 0, 0);
    }

    // bias + ReLU
    #pragma unroll
    for (int mf = 0; mf < 4; ++mf)
        #pragma unroll
        for (int i = 0; i < 4; ++i) {
            const float bv = a2.bias[pred][64 * wv + 16 * mf + q4 + i];
            #pragma unroll
            for (int sf = 0; sf < 4; ++sf)
                acc2[mf][sf][i] = fmaxf(acc2[mf][sf][i] + bv, 0.f);
        }

    // LN2 partials
    #pragma unroll
    for (int sf = 0; sf < 4; ++sf) {
        float s = 0.f, q = 0.f;
        #pragma unroll
        for (int mf = 0; mf < 4; ++mf)
            #pragma unroll
            for (int i = 0; i < 4; ++i) {
                const float v = acc2[mf][sf][i];
                s += v; q += v * v;
            }
        s += __shfl_xor(s, 16); s += __shfl_xor(s, 32);
        q += __shfl_xor(q, 16); q += __shfl_xor(q, 32);
        if (lane < 16) { red_s[16 * sf + lane][wv] = s; red_q[16 * sf + lane][wv] = q; }
    }
    __syncthreads();
    if (tid < 64) {
        const float s = red_s[tid][0] + red_s[tid][1] + red_s[tid][2] + red_s[tid][3];
        const float q = red_q[tid][0] + red_q[tid][1] + red_q[tid][2] + red_q[tid][3];
        const float mean = s * (1.f / 256.f);
        const float var  = q * (1.f / 256.f) - mean * mean;
        ln_m[tid] = mean;
        ln_r[tid] = rsqrtf(var + 1e-5f);
    }
    __syncthreads();

    // linear 256->1 + mask: in-reg dot over f2, 2 shuffles, cross-wave LDS
    {
        float c1v[4][4], cbv[4][4];
        #pragma unroll
        for (int mf = 0; mf < 4; ++mf)
            #pragma unroll
            for (int i = 0; i < 4; ++i) {
                const int f2 = 64 * wv + 16 * mf + q4 + i;
                const float lwv = a2.lw[pred][f2];
                c1v[mf][i] = a2.g[pred][f2] * lwv;
                cbv[mf][i] = a2.be[pred][f2] * lwv;
            }
        #pragma unroll
        for (int sf = 0; sf < 4; ++sf) {
            const int so = 16 * sf + ln15;
            const float mean = ln_m[so], rs = ln_r[so];
            float t = 0.f;
            #pragma unroll
            for (int mf = 0; mf < 4; ++mf)
                #pragma unroll
                for (int i = 0; i < 4; ++i)
                    t += (acc2[mf][sf][i] - mean) * rs * c1v[mf][i] + cbv[mf][i];
            t += __shfl_xor(t, 16); t += __shfl_xor(t, 32);
            if (lane < 16) red_s[16 * sf + lane][wv] = t;
        }
        __syncthreads();
        if (tid < 64) {
            const int gr = b * SS + s0 + tid;
            const float dv = red_s[tid][0] + red_s[tid][1] + red_s[tid][2] + red_s[tid][3]
                           + a2.lb[pred][0];
            a2.out[pred][gr] = mask[gr] ? 0.f : dv;
        }
    }
}

// ------- duration cumsum + d_rounded + mel_len + scatter expansion index -----
__global__ void dur_kernel(const int* __restrict__ dur, int* __restrict__ idxb,
                           int* __restrict__ mli,
                           float* __restrict__ drnd, float* __restrict__ mlen) {
    __shared__ int sb[SS];
    const int b = blockIdx.x, t = threadIdx.x;
    const int v = dur[b * SS + t];
    drnd[b * SS + t] = (float)v;
    sb[t] = v;
    __syncthreads();
    for (int off = 1; off < SS; off <<= 1) {
        const int add = (t >= off) ? sb[t - off] : 0;
        __syncthreads();
        sb[t] += add;
        __syncthreads();
    }
    const int hi = sb[t];
    const int lo = hi - v;
    for (int j = lo; j < hi; ++j) idxb[b * TT + j] = t;   // disjoint ranges
    if (t == SS - 1) { mlen[b] = (float)hi; mli[b] = hi; }
}

// ---------------- length regulator (precomputed idx, grid-stride) ------------
__global__ __launch_bounds__(256) void gather_kernel(
    const float* __restrict__ x,
    const float* __restrict__ ptab, const float* __restrict__ pt,
    const float* __restrict__ etab, const float* __restrict__ et,
    const int* __restrict__ idxb, const int* __restrict__ mli,
    float* __restrict__ mel)
{
    const int lane = threadIdx.x & 63;
    for (int row = blockIdx.x * 4 + (threadIdx.x >> 6); row < BB * TT; row += 4096 * 4) {
        const int b = row >> 11;
        const int t = row & (TT - 1);
        float4 v = make_float4(0.f, 0.f, 0.f, 0.f);
        if (t < mli[b]) {
            const int idx = idxb[row];
            const size_t src = ((size_t)b * SS + idx) * HH + lane * 4;
            v = *(const float4*)(x + src);
            const int pb = bucket256(pt[b * SS + idx]);
            const int eb = bucket256(et[b * SS + idx]);
            const float4 pv = *(const float4*)(ptab + (size_t)pb * HH + lane * 4);
            const float4 ev = *(const float4*)(etab + (size_t)eb * HH + lane * 4);
            v.x += pv.x + ev.x; v.y += pv.y + ev.y; v.z += pv.z + ev.z; v.w += pv.w + ev.w;
        }
        *(float4*)(mel + (size_t)row * HH + lane * 4) = v;
    }
}

// ---------------- launch -----------------------------------------------------
extern "C" void kernel_launch(void* const* d_in, const int* in_sizes, int n_in,
                              void* d_out, int out_size, void* d_ws, size_t ws_size,
                              hipStream_t stream) {
    (void)in_sizes; (void)n_in; (void)out_size; (void)ws_size;

    const float*   x      = (const float*)d_in[0];
    const float*   pitch  = (const float*)d_in[1];
    const float*   energy = (const float*)d_in[2];
    const uint8_t* mask   = (const uint8_t*)d_in[3];
    const int*     dur    = (const int*)d_in[4];
    const float*   ptab   = (const float*)d_in[36];
    const float*   etab   = (const float*)d_in[37];

    float* out = (float*)d_out;
    const size_t N_MEL = (size_t)BB * TT * HH;
    float* out_p  = out + N_MEL;
    float* out_e  = out_p + (size_t)BB * SS;
    float* out_ld = out_e + (size_t)BB * SS;
    float* out_dr = out_ld + (size_t)BB * SS;
    float* out_ml = out_dr + (size_t)BB * SS;

    // ws: packed weights (2.36 MB) | idxb (B*T int, 512 KB) | mli (64 int)
    bf16* wpk  = (bf16*)d_ws;
    int*  idxb = (int*)(wpk + 6 * WSZ);
    int*  mli  = idxb + (size_t)BB * TT;

    // scratch in the mel output region (134 MB, fully rewritten by gather):
    // x1 (16.8MB) | x2 (16.8MB)
    bf16* x1 = (bf16*)out;
    bf16* x2 = x1 + H1SZ;

    wt_pack<<<18, 256, 0, stream>>>(
        (const float*)d_in[6],  (const float*)d_in[10],
        (const float*)d_in[16], (const float*)d_in[20],
        (const float*)d_in[26], (const float*)d_in[30],
        wpk);
    xcvt_kernel<<<(BB * SS) / 8, 256, 0, stream>>>(x, pitch, ptab, x1, x2);
    dur_kernel<<<BB, SS, 0, stream>>>(dur, idxb, mli, out_dr, out_ml);

    Args3 a1 = {
        {(const float*)d_in[7],  (const float*)d_in[17], (const float*)d_in[27]},
        {(const float*)d_in[8],  (const float*)d_in[18], (const float*)d_in[28]},
        {(const float*)d_in[9],  (const float*)d_in[19], (const float*)d_in[29]},
        {nullptr, nullptr, nullptr}, {nullptr, nullptr, nullptr},
        {nullptr, nullptr, nullptr}
    };
    Args3 a2 = {
        {(const float*)d_in[11], (const float*)d_in[21], (const float*)d_in[31]},
        {(const float*)d_in[12], (const float*)d_in[22], (const float*)d_in[32]},
        {(const float*)d_in[13], (const float*)d_in[23], (const float*)d_in[33]},
        {(const float*)d_in[14], (const float*)d_in[24], (const float*)d_in[34]},
        {(const float*)d_in[15], (const float*)d_in[25], (const float*)d_in[35]},
        {out_ld, out_p, out_e}
    };

    conv_fused<<<3 * 512, 256, 0, stream>>>(x1, x2, wpk, a1, a2, mask);

    gather_kernel<<<4096, 256, 0, stream>>>(x, ptab, pitch, etab, energy, idxb, mli, out);
}

// Round 10
// 150.983 us; speedup vs baseline: 1.3330x; 1.0075x over previous
//
#include <hip/hip_runtime.h>
#include <cstdint>
#include <cstddef>

// VarianceAdaptor — R10: padded-stride LDS tile (264 bf16 = 528B rows) instead
// of XOR swizzle (R9's swizzle left bank bits 2-3 = 0 -> 8/32 banks used,
// 5.9M conflict cycles). Reg-staging (R6 showed ≡ gload_lds), affine K-loop
// addressing, bias folded into acc init. B=64,S=512,T=2048,H=F=256,K=3.

#define HH 256
#define SS 512
#define BB 64
#define TT 2048
#define LSTR 264   // padded LDS row stride in bf16 (528 B)

typedef __bf16 bf16;
typedef __attribute__((ext_vector_type(8))) __bf16 bf16x8;
typedef __attribute__((ext_vector_type(4))) __bf16 bf16x4;
typedef __attribute__((ext_vector_type(4))) float f32x4;

static constexpr size_t WSZ  = (size_t)3 * HH * HH;   // elems per conv weight
static constexpr size_t H1SZ = (size_t)BB * SS * HH;  // elems per x1/x2 buffer

// ---------------- bucket (searchsorted over jnp.linspace(-2,2,255) edges) ----
__device__ __forceinline__ float edge_val(int j) {
    const float step = 4.0f / 254.0f;
    if (j == 254) return 2.0f;
    return __fadd_rn(-2.0f, __fmul_rn((float)j, step));
}
__device__ __forceinline__ int bucket256(float v) {
    int lo = 0, hi = 255;
    while (lo < hi) {
        int mid = (lo + hi) >> 1;
        if (edge_val(mid) < v) lo = mid + 1; else hi = mid;
    }
    return lo;
}

// ------------- weight pack: w[k][c][f] f32 -> wp[k][fb][kcb][lane][8] bf16 ---
// frag: lane l holds [dim16 = fb*16 + (l&15)][k = kcb*32 + (l>>4)*8 + j]
__global__ void wt_pack(const float* __restrict__ w0, const float* __restrict__ w1,
                        const float* __restrict__ w2, const float* __restrict__ w3,
                        const float* __restrict__ w4, const float* __restrict__ w5,
                        bf16* __restrict__ wp) {
    const int cv = blockIdx.x / 3, k = blockIdx.x % 3;
    const float* wsel[6] = {w0, w1, w2, w3, w4, w5};
    const float* wk = wsel[cv] + (size_t)k * HH * HH;   // [c][f]
    bf16* o = wp + ((size_t)(cv * 3 + k)) * HH * HH;
    for (int fb = 0; fb < 16; ++fb) {
        #pragma unroll
        for (int h = 0; h < 2; ++h) {
            const int idx  = threadIdx.x + 256 * h;     // 0..511
            const int kcb  = idx >> 6, lane = idx & 63;
            const int f    = fb * 16 + (lane & 15);
            const int c0   = kcb * 32 + (lane >> 4) * 8;
            bf16x8 v;
            #pragma unroll
            for (int j = 0; j < 8; ++j) v[j] = (bf16)wk[(size_t)(c0 + j) * HH + f];
            *(bf16x8*)(o + (((size_t)fb * 8 + kcb) * 64 + lane) * 8) = v;
        }
    }
}

// ------------- x convert: x1 = bf16(x), x2 = bf16(x + p_table[bucket]) -------
__global__ __launch_bounds__(256) void xcvt_kernel(
    const float* __restrict__ x, const float* __restrict__ pt,
    const float* __restrict__ ptab,
    bf16* __restrict__ x1, bf16* __restrict__ x2)
{
    const int row = blockIdx.x * 8 + (threadIdx.x >> 5);   // 0 .. B*S-1
    const int c   = (threadIdx.x & 31) * 8;
    const int pb  = bucket256(pt[row]);
    const float4 v0 = *(const float4*)(x + (size_t)row * HH + c);
    const float4 v1 = *(const float4*)(x + (size_t)row * HH + c + 4);
    const float4 t0 = *(const float4*)(ptab + (size_t)pb * HH + c);
    const float4 t1 = *(const float4*)(ptab + (size_t)pb * HH + c + 4);
    bf16x8 a, b2;
    a[0] = (bf16)v0.x; a[1] = (bf16)v0.y; a[2] = (bf16)v0.z; a[3] = (bf16)v0.w;
    a[4] = (bf16)v1.x; a[5] = (bf16)v1.y; a[6] = (bf16)v1.z; a[7] = (bf16)v1.w;
    b2[0] = (bf16)(v0.x + t0.x); b2[1] = (bf16)(v0.y + t0.y);
    b2[2] = (bf16)(v0.z + t0.z); b2[3] = (bf16)(v0.w + t0.w);
    b2[4] = (bf16)(v1.x + t1.x); b2[5] = (bf16)(v1.y + t1.y);
    b2[6] = (bf16)(v1.z + t1.z); b2[7] = (bf16)(v1.w + t1.w);
    *(bf16x8*)(x1 + (size_t)row * HH + c) = a;
    *(bf16x8*)(x2 + (size_t)row * HH + c) = b2;
}

// ---------------- fused conv1+conv2, swapped-operand MFMA --------------------
struct Args3 {
    const float* bias[3];
    const float* g[3];
    const float* be[3];
    const float* lw[3];
    const float* lb[3];
    float*       out[3];
};

// grid = 3*512; 256 threads = 4 waves; wave wv owns f-rows [64wv, 64wv+64).
// X LDS tile: 82 rows, row r = seq s0-9+r. Stage1 output o = 16sf+ln15 maps
// to seq s0-8+o, o in [0,80); x row for tap k = o+k in [0,82). h rows
// hr = o-7 in [0,66), hr maps to seq s0-1+hr.
__global__ __launch_bounds__(256, 3) void conv_fused(
    const bf16* __restrict__ x1,      // (B,S,256) bf16
    const bf16* __restrict__ x2,      // (B,S,256) bf16 (x + p_emb), pred 2
    const bf16* __restrict__ wpk,     // packed weights, 6 convs
    Args3 a1, Args3 a2,
    const uint8_t* __restrict__ mask)
{
    __shared__ alignas(16) bf16 tile[82 * LSTR];        // 42.3KB: X, then h
    __shared__ float red_s[80][4], red_q[80][4];
    __shared__ float ln_m[80], ln_r[80];

    const int tid    = threadIdx.x;
    const int pred   = blockIdx.x >> 9;
    const int within = blockIdx.x & 511;
    const int b      = within >> 3;
    const int s0     = (within & 7) * 64;

    const int lane = tid & 63;
    const int wv   = tid >> 6;

    const bf16* inb = (pred == 2 ? x2 : x1) + (size_t)b * SS * HH;
    const bf16* wt1 = wpk + (size_t)(pred * 2) * WSZ;
    const bf16* wt2 = wt1 + WSZ;

    // ---- stage X tile: reg-staged, padded stride, halo zeroed in-reg ----
    for (int idx = tid; idx < 82 * 32; idx += 256) {
        const int r   = idx >> 5, c16 = idx & 31;
        const int s   = s0 - 9 + r;
        bf16x8 v = {};
        if (s >= 0 && s < SS)
            v = *(const bf16x8*)(inb + (size_t)s * HH + c16 * 8);
        *(bf16x8*)&tile[r * LSTR + c16 * 8] = v;
    }
    __syncthreads();

    const int ln15 = lane & 15;
    const int g8   = (lane >> 4) << 3;
    const int q4   = (lane >> 4) << 2;     // in-frag row quad base

    // ============ stage 1: D1[f1][o], f1-frag mf (4), o-tile sf (5) ==========
    f32x4 bini[4];
    #pragma unroll
    for (int mf = 0; mf < 4; ++mf)
        #pragma unroll
        for (int i = 0; i < 4; ++i)
            bini[mf][i] = a1.bias[pred][64 * wv + 16 * mf + q4 + i];

    f32x4 acc1[4][5];
    #pragma unroll
    for (int mf = 0; mf < 4; ++mf)
        #pragma unroll
        for (int sf = 0; sf < 5; ++sf) acc1[mf][sf] = bini[mf];

    #pragma unroll 2
    for (int t = 0; t < 24; ++t) {
        const int k = t >> 3, kcb = t & 7;
        const int kc = kcb << 5;
        bf16x8 aw[4], bx[5];
        const bf16* bp = wt1 + ((((size_t)k * 16 + wv * 4) * 8 + kcb) << 9)
                       + (size_t)lane * 8;
        #pragma unroll
        for (int mf = 0; mf < 4; ++mf)
            aw[mf] = *(const bf16x8*)(bp + ((size_t)mf << 12));
        #pragma unroll
        for (int sf = 0; sf < 5; ++sf)      // x row = o + tap k
            bx[sf] = *(const bf16x8*)&tile[(16 * sf + ln15 + k) * LSTR + kc + g8];
        #pragma unroll
        for (int mf = 0; mf < 4; ++mf)
            #pragma unroll
            for (int sf = 0; sf < 5; ++sf)
                acc1[mf][sf] = __builtin_amdgcn_mfma_f32_16x16x32_bf16(
                    aw[mf], bx[sf], acc1[mf][sf], 0, 0, 0);
    }

    // ReLU
    #pragma unroll
    for (int mf = 0; mf < 4; ++mf)
        #pragma unroll
        for (int sf = 0; sf < 5; ++sf)
            #pragma unroll
            for (int i = 0; i < 4; ++i)
                acc1[mf][sf][i] = fmaxf(acc1[mf][sf][i], 0.f);

    // LN1 partials: per o, sum over f1 = 16 in-reg values + 2 shuffles
    #pragma unroll
    for (int sf = 0; sf < 5; ++sf) {
        float s = 0.f, q = 0.f;
        #pragma unroll
        for (int mf = 0; mf < 4; ++mf)
            #pragma unroll
            for (int i = 0; i < 4; ++i) {
                const float v = acc1[mf][sf][i];
                s += v; q += v * v;
            }
        s += __shfl_xor(s, 16); s += __shfl_xor(s, 32);
        q += __shfl_xor(q, 16); q += __shfl_xor(q, 32);
        if (lane < 16) { red_s[16 * sf + lane][wv] = s; red_q[16 * sf + lane][wv] = q; }
    }
    __syncthreads();
    if (tid < 80) {
        const float s = red_s[tid][0] + red_s[tid][1] + red_s[tid][2] + red_s[tid][3];
        const float q = red_q[tid][0] + red_q[tid][1] + red_q[tid][2] + red_q[tid][3];
        const float mean = s * (1.f / 256.f);
        const float var  = q * (1.f / 256.f) - mean * mean;
        ln_m[tid] = mean;
        ln_r[tid] = rsqrtf(var + 1e-5f);
    }
    __syncthreads();

    // h-write: packed b64 (4 consecutive f1 at one o), rows hr = o-7 in [0,66)
    {
        float g1v[4][4], be1v[4][4];
        #pragma unroll
        for (int mf = 0; mf < 4; ++mf)
            #pragma unroll
            for (int i = 0; i < 4; ++i) {
                const int f1 = 64 * wv + 16 * mf + q4 + i;
                g1v[mf][i]  = a1.g[pred][f1];
                be1v[mf][i] = a1.be[pred][f1];
            }
        #pragma unroll
        for (int sf = 0; sf < 5; ++sf) {
            const int o  = 16 * sf + ln15;
            const int hr = o - 7;
            const float mean = ln_m[o], rs = ln_r[o];
            const bool ok = (o >= 7 && o <= 72);
            #pragma unroll
            for (int mf = 0; mf < 4; ++mf) {
                bf16x4 hv;
                #pragma unroll
                for (int i = 0; i < 4; ++i)
                    hv[i] = (bf16)((acc1[mf][sf][i] - mean) * rs * g1v[mf][i] + be1v[mf][i]);
                if (ok)
                    *(bf16x4*)&tile[hr * LSTR + 64 * wv + 16 * mf + q4] = hv;
            }
        }
    }
    __syncthreads();
    // zero h halo rows at batch edges (conv2 zero-padding)
    if (tid < 64) {
        if (s0 == 0)       *(uint2*)&tile[tid * 4]            = make_uint2(0u, 0u);
        if (s0 == SS - 64) *(uint2*)&tile[65 * LSTR + tid * 4] = make_uint2(0u, 0u);
    }
    __syncthreads();

    // ============ stage 2: D2[f2][so], so-tile sf (4) ==========
    #pragma unroll
    for (int mf = 0; mf < 4; ++mf)
        #pragma unroll
        for (int i = 0; i < 4; ++i)
            bini[mf][i] = a2.bias[pred][64 * wv + 16 * mf + q4 + i];

    f32x4 acc2[4][4];
    #pragma unroll
    for (int mf = 0; mf < 4; ++mf)
        #pragma unroll
        for (int sf = 0; sf < 4; ++sf) acc2[mf][sf] = bini[mf];

    #pragma unroll 2
    for (int t = 0; t < 24; ++t) {
        const int k = t >> 3, kcb = t & 7;
        const int kc = kcb << 5;
        bf16x8 aw[4], bx[4];
        const bf16* bp = wt2 + ((((size_t)k * 16 + wv * 4) * 8 + kcb) << 9)
                       + (size_t)lane * 8;
        #pragma unroll
        for (int mf = 0; mf < 4; ++mf)
            aw[mf] = *(const bf16x8*)(bp + ((size_t)mf << 12));
        #pragma unroll
        for (int sf = 0; sf < 4; ++sf)      // h row = so + tap k
            bx[sf] = *(const bf16x8*)&tile[(16 * sf + ln15 + k) * LSTR + kc + g8];
        #pragma unroll
        for (int mf = 0; mf < 4; ++mf)
            #pragma unroll
            for (int sf = 0; sf < 4; ++sf)
                acc2[mf][sf] = __builtin_amdgcn_mfma_f32_16x16x32_bf16(
                    aw[mf], bx[sf], acc2[mf][sf], 0, 0, 0);
    }

    // ReLU
    #pragma unroll
    for (int mf = 0; mf < 4; ++mf)
        #pragma unroll
        for (int sf = 0; sf < 4; ++sf)
            #pragma unroll
            for (int i = 0; i < 4; ++i)
                acc2[mf][sf][i] = fmaxf(acc2[mf][sf][i], 0.f);

    // LN2 partials
    #pragma unroll
    for (int sf = 0; sf < 4; ++sf) {
        float s = 0.f, q = 0.f;
        #pragma unroll
        for (int mf = 0; mf < 4; ++mf)
            #pragma unroll
            for (int i = 0; i < 4; ++i) {
                const float v = acc2[mf][sf][i];
                s += v; q += v * v;
            }
        s += __shfl_xor(s, 16); s += __shfl_xor(s, 32);
        q += __shfl_xor(q, 16); q += __shfl_xor(q, 32);
        if (lane < 16) { red_s[16 * sf + lane][wv] = s; red_q[16 * sf + lane][wv] = q; }
    }
    __syncthreads();
    if (tid < 64) {
        const float s = red_s[tid][0] + red_s[tid][1] + red_s[tid][2] + red_s[tid][3];
        const float q = red_q[tid][0] + red_q[tid][1] + red_q[tid][2] + red_q[tid][3];
        const float mean = s * (1.f / 256.f);
        const float var  = q * (1.f / 256.f) - mean * mean;
        ln_m[tid] = mean;
        ln_r[tid] = rsqrtf(var + 1e-5f);
    }
    __syncthreads();

    // linear 256->1 + mask: in-reg dot over f2, 2 shuffles, cross-wave LDS
    {
        float c1v[4][4], cbv[4][4];
        #pragma unroll
        for (int mf = 0; mf < 4; ++mf)
            #pragma unroll
            for (int i = 0; i < 4; ++i) {
                const int f2 = 64 * wv + 16 * mf + q4 + i;
                const float lwv = a2.lw[pred][f2];
                c1v[mf][i] = a2.g[pred][f2] * lwv;
                cbv[mf][i] = a2.be[pred][f2] * lwv;
            }
        #pragma unroll
        for (int sf = 0; sf < 4; ++sf) {
            const int so = 16 * sf + ln15;
            const float mean = ln_m[so], rs = ln_r[so];
            float t = 0.f;
            #pragma unroll
            for (int mf = 0; mf < 4; ++mf)
                #pragma unroll
                for (int i = 0; i < 4; ++i)
                    t += (acc2[mf][sf][i] - mean) * rs * c1v[mf][i] + cbv[mf][i];
            t += __shfl_xor(t, 16); t += __shfl_xor(t, 32);
            if (lane < 16) red_s[16 * sf + lane][wv] = t;
        }
        __syncthreads();
        if (tid < 64) {
            const int gr = b * SS + s0 + tid;
            const float dv = red_s[tid][0] + red_s[tid][1] + red_s[tid][2] + red_s[tid][3]
                           + a2.lb[pred][0];
            a2.out[pred][gr] = mask[gr] ? 0.f : dv;
        }
    }
}

// ------- duration cumsum + d_rounded + mel_len + scatter expansion index -----
__global__ void dur_kernel(const int* __restrict__ dur, int* __restrict__ idxb,
                           int* __restrict__ mli,
                           float* __restrict__ drnd, float* __restrict__ mlen) {
    __shared__ int sb[SS];
    const int b = blockIdx.x, t = threadIdx.x;
    const int v = dur[b * SS + t];
    drnd[b * SS + t] = (float)v;
    sb[t] = v;
    __syncthreads();
    for (int off = 1; off < SS; off <<= 1) {
        const int add = (t >= off) ? sb[t - off] : 0;
        __syncthreads();
        sb[t] += add;
        __syncthreads();
    }
    const int hi = sb[t];
    const int lo = hi - v;
    for (int j = lo; j < hi; ++j) idxb[b * TT + j] = t;   // disjoint ranges
    if (t == SS - 1) { mlen[b] = (float)hi; mli[b] = hi; }
}

// ---------------- length regulator (precomputed idx, grid-stride) ------------
__global__ __launch_bounds__(256) void gather_kernel(
    const float* __restrict__ x,
    const float* __restrict__ ptab, const float* __restrict__ pt,
    const float* __restrict__ etab, const float* __restrict__ et,
    const int* __restrict__ idxb, const int* __restrict__ mli,
    float* __restrict__ mel)
{
    const int lane = threadIdx.x & 63;
    for (int row = blockIdx.x * 4 + (threadIdx.x >> 6); row < BB * TT; row += 4096 * 4) {
        const int b = row >> 11;
        const int t = row & (TT - 1);
        float4 v = make_float4(0.f, 0.f, 0.f, 0.f);
        if (t < mli[b]) {
            const int idx = idxb[row];
            const size_t src = ((size_t)b * SS + idx) * HH + lane * 4;
            v = *(const float4*)(x + src);
            const int pb = bucket256(pt[b * SS + idx]);
            const int eb = bucket256(et[b * SS + idx]);
            const float4 pv = *(const float4*)(ptab + (size_t)pb * HH + lane * 4);
            const float4 ev = *(const float4*)(etab + (size_t)eb * HH + lane * 4);
            v.x += pv.x + ev.x; v.y += pv.y + ev.y; v.z += pv.z + ev.z; v.w += pv.w + ev.w;
        }
        *(float4*)(mel + (size_t)row * HH + lane * 4) = v;
    }
}

// ---------------- launch -----------------------------------------------------
extern "C" void kernel_launch(void* const* d_in, const int* in_sizes, int n_in,
                              void* d_out, int out_size, void* d_ws, size_t ws_size,
                              hipStream_t stream) {
    (void)in_sizes; (void)n_in; (void)out_size; (void)ws_size;

    const float*   x      = (const float*)d_in[0];
    const float*   pitch  = (const float*)d_in[1];
    const float*   energy = (const float*)d_in[2];
    const uint8_t* mask   = (const uint8_t*)d_in[3];
    const int*     dur    = (const int*)d_in[4];
    const float*   ptab   = (const float*)d_in[36];
    const float*   etab   = (const float*)d_in[37];

    float* out = (float*)d_out;
    const size_t N_MEL = (size_t)BB * TT * HH;
    float* out_p  = out + N_MEL;
    float* out_e  = out_p + (size_t)BB * SS;
    float* out_ld = out_e + (size_t)BB * SS;
    float* out_dr = out_ld + (size_t)BB * SS;
    float* out_ml = out_dr + (size_t)BB * SS;

    // ws: packed weights (2.36 MB) | idxb (B*T int, 512 KB) | mli (64 int)
    bf16* wpk  = (bf16*)d_ws;
    int*  idxb = (int*)(wpk + 6 * WSZ);
    int*  mli  = idxb + (size_t)BB * TT;

    // scratch in the mel output region (134 MB, fully rewritten by gather):
    // x1 (16.8MB) | x2 (16.8MB)
    bf16* x1 = (bf16*)out;
    bf16* x2 = x1 + H1SZ;

    wt_pack<<<18, 256, 0, stream>>>(
        (const float*)d_in[6],  (const float*)d_in[10],
        (const float*)d_in[16], (const float*)d_in[20],
        (const float*)d_in[26], (const float*)d_in[30],
        wpk);
    xcvt_kernel<<<(BB * SS) / 8, 256, 0, stream>>>(x, pitch, ptab, x1, x2);
    dur_kernel<<<BB, SS, 0, stream>>>(dur, idxb, mli, out_dr, out_ml);

    Args3 a1 = {
        {(const float*)d_in[7],  (const float*)d_in[17], (const float*)d_in[27]},
        {(const float*)d_in[8],  (const float*)d_in[18], (const float*)d_in[28]},
        {(const float*)d_in[9],  (const float*)d_in[19], (const float*)d_in[29]},
        {nullptr, nullptr, nullptr}, {nullptr, nullptr, nullptr},
        {nullptr, nullptr, nullptr}
    };
    Args3 a2 = {
        {(const float*)d_in[11], (const float*)d_in[21], (const float*)d_in[31]},
        {(const float*)d_in[12], (const float*)d_in[22], (const float*)d_in[32]},
        {(const float*)d_in[13], (const float*)d_in[23], (const float*)d_in[33]},
        {(const float*)d_in[14], (const float*)d_in[24], (const float*)d_in[34]},
        {(const float*)d_in[15], (const float*)d_in[25], (const float*)d_in[35]},
        {out_ld, out_p, out_e}
    };

    conv_fused<<<3 * 512, 256, 0, stream>>>(x1, x2, wpk, a1, a2, mask);

    gather_kernel<<<4096, 256, 0, stream>>>(x, ptab, pitch, etab, energy, idxb, mli, out);
}

// Round 11
// 132.042 us; speedup vs baseline: 1.5242x; 1.1434x over previous
//
#include <hip/hip_runtime.h>
#include <cstdint>
#include <cstddef>

// VarianceAdaptor — R11: T5 setprio around MFMA clusters (3 blocks/CU at
// different phases -> role diversity), stage2 weight prefetch issued before
// LN1 (T14 issue-early), wt_pack+dur+xcvt merged into one prep dispatch.
// B=64, S=512, T=2048, H=F=256, K=3, NBINS=256.

#define HH 256
#define SS 512
#define BB 64
#define TT 2048
#define LSTR 264   // padded LDS row stride in bf16 (528 B)

typedef __bf16 bf16;
typedef __attribute__((ext_vector_type(8))) __bf16 bf16x8;
typedef __attribute__((ext_vector_type(4))) __bf16 bf16x4;
typedef __attribute__((ext_vector_type(4))) float f32x4;

static constexpr size_t WSZ  = (size_t)3 * HH * HH;   // elems per conv weight
static constexpr size_t H1SZ = (size_t)BB * SS * HH;  // elems per x1/x2 buffer

// ---------------- bucket (searchsorted over jnp.linspace(-2,2,255) edges) ----
__device__ __forceinline__ float edge_val(int j) {
    const float step = 4.0f / 254.0f;
    if (j == 254) return 2.0f;
    return __fadd_rn(-2.0f, __fmul_rn((float)j, step));
}
__device__ __forceinline__ int bucket256(float v) {
    int lo = 0, hi = 255;
    while (lo < hi) {
        int mid = (lo + hi) >> 1;
        if (edge_val(mid) < v) lo = mid + 1; else hi = mid;
    }
    return lo;
}

// ---------------- merged prep: wt_pack | dur scan | x convert ---------------
// blocks [0,18): weight pack  w[k][c][f] f32 -> wp[k][fb][kcb][lane][8] bf16
// blocks [18,82): duration cumsum + scatter index (one batch row per block)
// blocks [82,4178): x1 = bf16(x), x2 = bf16(x + p_table[bucket(pitch)])
__global__ __launch_bounds__(256) void prep_kernel(
    const float* __restrict__ w0, const float* __restrict__ w1,
    const float* __restrict__ w2, const float* __restrict__ w3,
    const float* __restrict__ w4, const float* __restrict__ w5,
    bf16* __restrict__ wp,
    const int* __restrict__ dur, int* __restrict__ idxb, int* __restrict__ mli,
    float* __restrict__ drnd, float* __restrict__ mlen,
    const float* __restrict__ x, const float* __restrict__ pt,
    const float* __restrict__ ptab,
    bf16* __restrict__ x1, bf16* __restrict__ x2)
{
    const int tid = threadIdx.x;
    if (blockIdx.x < 18) {
        const int cv = blockIdx.x / 3, k = blockIdx.x % 3;
        const float* wsel[6] = {w0, w1, w2, w3, w4, w5};
        const float* wk = wsel[cv] + (size_t)k * HH * HH;   // [c][f]
        bf16* o = wp + ((size_t)(cv * 3 + k)) * HH * HH;
        for (int fb = 0; fb < 16; ++fb) {
            #pragma unroll
            for (int h = 0; h < 2; ++h) {
                const int idx  = tid + 256 * h;             // 0..511
                const int kcb  = idx >> 6, lane = idx & 63;
                const int f    = fb * 16 + (lane & 15);
                const int c0   = kcb * 32 + (lane >> 4) * 8;
                bf16x8 v;
                #pragma unroll
                for (int j = 0; j < 8; ++j) v[j] = (bf16)wk[(size_t)(c0 + j) * HH + f];
                *(bf16x8*)(o + (((size_t)fb * 8 + kcb) * 64 + lane) * 8) = v;
            }
        }
    } else if (blockIdx.x < 82) {
        __shared__ int sb[SS];
        const int b = blockIdx.x - 18;
        const int d0 = dur[b * SS + tid];
        const int d1 = dur[b * SS + tid + 256];
        drnd[b * SS + tid]       = (float)d0;
        drnd[b * SS + tid + 256] = (float)d1;
        sb[tid]       = d0;
        sb[tid + 256] = d1;
        __syncthreads();
        for (int off = 1; off < SS; off <<= 1) {
            const int a0 = (tid >= off) ? sb[tid - off] : 0;
            const int a1 = (tid + 256 >= off) ? sb[tid + 256 - off] : 0;
            __syncthreads();
            sb[tid] += a0;
            sb[tid + 256] += a1;
            __syncthreads();
        }
        {
            const int hi = sb[tid], lo = hi - d0;
            for (int j = lo; j < hi; ++j) idxb[b * TT + j] = tid;
        }
        {
            const int hi = sb[tid + 256], lo = hi - d1;
            for (int j = lo; j < hi; ++j) idxb[b * TT + j] = tid + 256;
        }
        if (tid == 255) { mlen[b] = (float)sb[SS - 1]; mli[b] = sb[SS - 1]; }
    } else {
        const int row = (blockIdx.x - 82) * 8 + (tid >> 5);   // 0 .. B*S-1
        const int c   = (tid & 31) * 8;
        const int pb  = bucket256(pt[row]);
        const float4 v0 = *(const float4*)(x + (size_t)row * HH + c);
        const float4 v1 = *(const float4*)(x + (size_t)row * HH + c + 4);
        const float4 t0 = *(const float4*)(ptab + (size_t)pb * HH + c);
        const float4 t1 = *(const float4*)(ptab + (size_t)pb * HH + c + 4);
        bf16x8 a, b2;
        a[0] = (bf16)v0.x; a[1] = (bf16)v0.y; a[2] = (bf16)v0.z; a[3] = (bf16)v0.w;
        a[4] = (bf16)v1.x; a[5] = (bf16)v1.y; a[6] = (bf16)v1.z; a[7] = (bf16)v1.w;
        b2[0] = (bf16)(v0.x + t0.x); b2[1] = (bf16)(v0.y + t0.y);
        b2[2] = (bf16)(v0.z + t0.z); b2[3] = (bf16)(v0.w + t0.w);
        b2[4] = (bf16)(v1.x + t1.x); b2[5] = (bf16)(v1.y + t1.y);
        b2[6] = (bf16)(v1.z + t1.z); b2[7] = (bf16)(v1.w + t1.w);
        *(bf16x8*)(x1 + (size_t)row * HH + c) = a;
        *(bf16x8*)(x2 + (size_t)row * HH + c) = b2;
    }
}

// ---------------- fused conv1+conv2, swapped-operand MFMA --------------------
struct Args3 {
    const float* bias[3];
    const float* g[3];
    const float* be[3];
    const float* lw[3];
    const float* lb[3];
    float*       out[3];
};

// grid = 3*512; 256 threads = 4 waves; wave wv owns f-rows [64wv, 64wv+64).
__global__ __launch_bounds__(256, 3) void conv_fused(
    const bf16* __restrict__ x1,      // (B,S,256) bf16
    const bf16* __restrict__ x2,      // (B,S,256) bf16 (x + p_emb), pred 2
    const bf16* __restrict__ wpk,     // packed weights, 6 convs
    Args3 a1, Args3 a2,
    const uint8_t* __restrict__ mask)
{
    __shared__ alignas(16) bf16 tile[82 * LSTR];        // 42.3KB: X, then h
    __shared__ float red_s[80][4], red_q[80][4];
    __shared__ float ln_m[80], ln_r[80];

    const int tid    = threadIdx.x;
    const int pred   = blockIdx.x >> 9;
    const int within = blockIdx.x & 511;
    const int b      = within >> 3;
    const int s0     = (within & 7) * 64;

    const int lane = tid & 63;
    const int wv   = tid >> 6;

    const bf16* inb = (pred == 2 ? x2 : x1) + (size_t)b * SS * HH;
    const bf16* wt1 = wpk + (size_t)(pred * 2) * WSZ;
    const bf16* wt2 = wt1 + WSZ;

    // ---- stage X tile: reg-staged, padded stride, halo zeroed in-reg ----
    for (int idx = tid; idx < 82 * 32; idx += 256) {
        const int r   = idx >> 5, c16 = idx & 31;
        const int s   = s0 - 9 + r;
        bf16x8 v = {};
        if (s >= 0 && s < SS)
            v = *(const bf16x8*)(inb + (size_t)s * HH + c16 * 8);
        *(bf16x8*)&tile[r * LSTR + c16 * 8] = v;
    }
    __syncthreads();

    const int ln15 = lane & 15;
    const int g8   = (lane >> 4) << 3;
    const int q4   = (lane >> 4) << 2;     // in-frag row quad base

    // ============ stage 1: D1[f1][o], f1-frag mf (4), o-tile sf (5) ==========
    f32x4 bini[4];
    #pragma unroll
    for (int mf = 0; mf < 4; ++mf)
        #pragma unroll
        for (int i = 0; i < 4; ++i)
            bini[mf][i] = a1.bias[pred][64 * wv + 16 * mf + q4 + i];

    f32x4 acc1[4][5];
    #pragma unroll
    for (int mf = 0; mf < 4; ++mf)
        #pragma unroll
        for (int sf = 0; sf < 5; ++sf) acc1[mf][sf] = bini[mf];

    #pragma unroll 2
    for (int t = 0; t < 24; ++t) {
        const int k = t >> 3, kcb = t & 7;
        const int kc = kcb << 5;
        bf16x8 aw[4], bx[5];
        const bf16* bp = wt1 + ((((size_t)k * 16 + wv * 4) * 8 + kcb) << 9)
                       + (size_t)lane * 8;
        #pragma unroll
        for (int mf = 0; mf < 4; ++mf)
            aw[mf] = *(const bf16x8*)(bp + ((size_t)mf << 12));
        #pragma unroll
        for (int sf = 0; sf < 5; ++sf)      // x row = o + tap k
            bx[sf] = *(const bf16x8*)&tile[(16 * sf + ln15 + k) * LSTR + kc + g8];
        __builtin_amdgcn_s_setprio(1);
        #pragma unroll
        for (int mf = 0; mf < 4; ++mf)
            #pragma unroll
            for (int sf = 0; sf < 5; ++sf)
                acc1[mf][sf] = __builtin_amdgcn_mfma_f32_16x16x32_bf16(
                    aw[mf], bx[sf], acc1[mf][sf], 0, 0, 0);
        __builtin_amdgcn_s_setprio(0);
    }

    // T14 issue-early: stage2 t=0 weight frags, latency hidden under LN1+h-write
    bf16x8 aw20[4];
    {
        const bf16* bp2 = wt2 + (((size_t)wv * 4) * 8 << 9) + (size_t)lane * 8;
        #pragma unroll
        for (int mf = 0; mf < 4; ++mf)
            aw20[mf] = *(const bf16x8*)(bp2 + ((size_t)mf << 12));
    }

    // ReLU
    #pragma unroll
    for (int mf = 0; mf < 4; ++mf)
        #pragma unroll
        for (int sf = 0; sf < 5; ++sf)
            #pragma unroll
            for (int i = 0; i < 4; ++i)
                acc1[mf][sf][i] = fmaxf(acc1[mf][sf][i], 0.f);

    // LN1 partials: per o, sum over f1 = 16 in-reg values + 2 shuffles
    #pragma unroll
    for (int sf = 0; sf < 5; ++sf) {
        float s = 0.f, q = 0.f;
        #pragma unroll
        for (int mf = 0; mf < 4; ++mf)
            #pragma unroll
            for (int i = 0; i < 4; ++i) {
                const float v = acc1[mf][sf][i];
                s += v; q += v * v;
            }
        s += __shfl_xor(s, 16); s += __shfl_xor(s, 32);
        q += __shfl_xor(q, 16); q += __shfl_xor(q, 32);
        if (lane < 16) { red_s[16 * sf + lane][wv] = s; red_q[16 * sf + lane][wv] = q; }
    }
    __syncthreads();
    if (tid < 80) {
        const float s = red_s[tid][0] + red_s[tid][1] + red_s[tid][2] + red_s[tid][3];
        const float q = red_q[tid][0] + red_q[tid][1] + red_q[tid][2] + red_q[tid][3];
        const float mean = s * (1.f / 256.f);
        const float var  = q * (1.f / 256.f) - mean * mean;
        ln_m[tid] = mean;
        ln_r[tid] = rsqrtf(var + 1e-5f);
    }
    __syncthreads();

    // h-write: packed b64 (4 consecutive f1 at one o), rows hr = o-7 in [0,66)
    {
        float g1v[4][4], be1v[4][4];
        #pragma unroll
        for (int mf = 0; mf < 4; ++mf)
            #pragma unroll
            for (int i = 0; i < 4; ++i) {
                const int f1 = 64 * wv + 16 * mf + q4 + i;
                g1v[mf][i]  = a1.g[pred][f1];
                be1v[mf][i] = a1.be[pred][f1];
            }
        #pragma unroll
        for (int sf = 0; sf < 5; ++sf) {
            const int o  = 16 * sf + ln15;
            const int hr = o - 7;
            const float mean = ln_m[o], rs = ln_r[o];
            const bool ok = (o >= 7 && o <= 72);
            #pragma unroll
            for (int mf = 0; mf < 4; ++mf) {
                bf16x4 hv;
                #pragma unroll
                for (int i = 0; i < 4; ++i)
                    hv[i] = (bf16)((acc1[mf][sf][i] - mean) * rs * g1v[mf][i] + be1v[mf][i]);
                if (ok)
                    *(bf16x4*)&tile[hr * LSTR + 64 * wv + 16 * mf + q4] = hv;
            }
        }
    }
    __syncthreads();
    // zero h halo rows at batch edges (conv2 zero-padding)
    if (tid < 64) {
        if (s0 == 0)       *(uint2*)&tile[tid * 4]            = make_uint2(0u, 0u);
        if (s0 == SS - 64) *(uint2*)&tile[65 * LSTR + tid * 4] = make_uint2(0u, 0u);
    }
    __syncthreads();

    // ============ stage 2: D2[f2][so], so-tile sf (4) ==========
    #pragma unroll
    for (int mf = 0; mf < 4; ++mf)
        #pragma unroll
        for (int i = 0; i < 4; ++i)
            bini[mf][i] = a2.bias[pred][64 * wv + 16 * mf + q4 + i];

    f32x4 acc2[4][4];
    #pragma unroll
    for (int mf = 0; mf < 4; ++mf)
        #pragma unroll
        for (int sf = 0; sf < 4; ++sf) acc2[mf][sf] = bini[mf];

#define S2_STEP(AW_, K_, KCB_) do {                                            \
    const int kc_ = (KCB_) << 5;                                               \
    bf16x8 bx_[4];                                                             \
    _Pragma("unroll")                                                          \
    for (int sf_ = 0; sf_ < 4; ++sf_)                                          \
        bx_[sf_] = *(const bf16x8*)&tile[(16 * sf_ + ln15 + (K_)) * LSTR       \
                                         + kc_ + g8];                          \
    __builtin_amdgcn_s_setprio(1);                                             \
    _Pragma("unroll")                                                          \
    for (int mf_ = 0; mf_ < 4; ++mf_)                                          \
        _Pragma("unroll")                                                      \
        for (int sf_ = 0; sf_ < 4; ++sf_)                                      \
            acc2[mf_][sf_] = __builtin_amdgcn_mfma_f32_16x16x32_bf16(          \
                AW_[mf_], bx_[sf_], acc2[mf_][sf_], 0, 0, 0);                  \
    __builtin_amdgcn_s_setprio(0);                                             \
} while (0)

    // t = 0 peeled: weights already in aw20 (prefetched before LN1)
    S2_STEP(aw20, 0, 0);
    #pragma unroll 2
    for (int t = 1; t < 24; ++t) {
        const int k = t >> 3, kcb = t & 7;
        bf16x8 aw[4];
        const bf16* bp = wt2 + ((((size_t)k * 16 + wv * 4) * 8 + kcb) << 9)
                       + (size_t)lane * 8;
        #pragma unroll
        for (int mf = 0; mf < 4; ++mf)
            aw[mf] = *(const bf16x8*)(bp + ((size_t)mf << 12));
        S2_STEP(aw, k, kcb);
    }
#undef S2_STEP

    // ReLU
    #pragma unroll
    for (int mf = 0; mf < 4; ++mf)
        #pragma unroll
        for (int sf = 0; sf < 4; ++sf)
            #pragma unroll
            for (int i = 0; i < 4; ++i)
                acc2[mf][sf][i] = fmaxf(acc2[mf][sf][i], 0.f);

    // LN2 partials
    #pragma unroll
    for (int sf = 0; sf < 4; ++sf) {
        float s = 0.f, q = 0.f;
        #pragma unroll
        for (int mf = 0; mf < 4; ++mf)
            #pragma unroll
            for (int i = 0; i < 4; ++i) {
                const float v = acc2[mf][sf][i];
                s += v; q += v * v;
            }
        s += __shfl_xor(s, 16); s += __shfl_xor(s, 32);
        q += __shfl_xor(q, 16); q += __shfl_xor(q, 32);
        if (lane < 16) { red_s[16 * sf + lane][wv] = s; red_q[16 * sf + lane][wv] = q; }
    }
    __syncthreads();
    if (tid < 64) {
        const float s = red_s[tid][0] + red_s[tid][1] + red_s[tid][2] + red_s[tid][3];
        const float q = red_q[tid][0] + red_q[tid][1] + red_q[tid][2] + red_q[tid][3];
        const float mean = s * (1.f / 256.f);
        const float var  = q * (1.f / 256.f) - mean * mean;
        ln_m[tid] = mean;
        ln_r[tid] = rsqrtf(var + 1e-5f);
    }
    __syncthreads();

    // linear 256->1 + mask: in-reg dot over f2, 2 shuffles, cross-wave LDS
    {
        float c1v[4][4], cbv[4][4];
        #pragma unroll
        for (int mf = 0; mf < 4; ++mf)
            #pragma unroll
            for (int i = 0; i < 4; ++i) {
                const int f2 = 64 * wv + 16 * mf + q4 + i;
                const float lwv = a2.lw[pred][f2];
                c1v[mf][i] = a2.g[pred][f2] * lwv;
                cbv[mf][i] = a2.be[pred][f2] * lwv;
            }
        #pragma unroll
        for (int sf = 0; sf < 4; ++sf) {
            const int so = 16 * sf + ln15;
            const float mean = ln_m[so], rs = ln_r[so];
            float t = 0.f;
            #pragma unroll
            for (int mf = 0; mf < 4; ++mf)
                #pragma unroll
                for (int i = 0; i < 4; ++i)
                    t += (acc2[mf][sf][i] - mean) * rs * c1v[mf][i] + cbv[mf][i];
            t += __shfl_xor(t, 16); t += __shfl_xor(t, 32);
            if (lane < 16) red_s[16 * sf + lane][wv] = t;
        }
        __syncthreads();
        if (tid < 64) {
            const int gr = b * SS + s0 + tid;
            const float dv = red_s[tid][0] + red_s[tid][1] + red_s[tid][2] + red_s[tid][3]
                           + a2.lb[pred][0];
            a2.out[pred][gr] = mask[gr] ? 0.f : dv;
        }
    }
}

// ---------------- length regulator (precomputed idx, grid-stride) ------------
__global__ __launch_bounds__(256) void gather_kernel(
    const float* __restrict__ x,
    const float* __restrict__ ptab, const float* __restrict__ pt,
    const float* __restrict__ etab, const float* __restrict__ et,
    const int* __restrict__ idxb, const int* __restrict__ mli,
    float* __restrict__ mel)
{
    const int lane = threadIdx.x & 63;
    for (int row = blockIdx.x * 4 + (threadIdx.x >> 6); row < BB * TT; row += 4096 * 4) {
        const int b = row >> 11;
        const int t = row & (TT - 1);
        float4 v = make_float4(0.f, 0.f, 0.f, 0.f);
        if (t < mli[b]) {
            const int idx = idxb[row];
            const size_t src = ((size_t)b * SS + idx) * HH + lane * 4;
            v = *(const float4*)(x + src);
            const int pb = bucket256(pt[b * SS + idx]);
            const int eb = bucket256(et[b * SS + idx]);
            const float4 pv = *(const float4*)(ptab + (size_t)pb * HH + lane * 4);
            const float4 ev = *(const float4*)(etab + (size_t)eb * HH + lane * 4);
            v.x += pv.x + ev.x; v.y += pv.y + ev.y; v.z += pv.z + ev.z; v.w += pv.w + ev.w;
        }
        *(float4*)(mel + (size_t)row * HH + lane * 4) = v;
    }
}

// ---------------- launch -----------------------------------------------------
extern "C" void kernel_launch(void* const* d_in, const int* in_sizes, int n_in,
                              void* d_out, int out_size, void* d_ws, size_t ws_size,
                              hipStream_t stream) {
    (void)in_sizes; (void)n_in; (void)out_size; (void)ws_size;

    const float*   x      = (const float*)d_in[0];
    const float*   pitch  = (const float*)d_in[1];
    const float*   energy = (const float*)d_in[2];
    const uint8_t* mask   = (const uint8_t*)d_in[3];
    const int*     dur    = (const int*)d_in[4];
    const float*   ptab   = (const float*)d_in[36];
    const float*   etab   = (const float*)d_in[37];

    float* out = (float*)d_out;
    const size_t N_MEL = (size_t)BB * TT * HH;
    float* out_p  = out + N_MEL;
    float* out_e  = out_p + (size_t)BB * SS;
    float* out_ld = out_e + (size_t)BB * SS;
    float* out_dr = out_ld + (size_t)BB * SS;
    float* out_ml = out_dr + (size_t)BB * SS;

    // ws: packed weights (2.36 MB) | idxb (B*T int, 512 KB) | mli (64 int)
    bf16* wpk  = (bf16*)d_ws;
    int*  idxb = (int*)(wpk + 6 * WSZ);
    int*  mli  = idxb + (size_t)BB * TT;

    // scratch in the mel output region (134 MB, fully rewritten by gather):
    // x1 (16.8MB) | x2 (16.8MB)
    bf16* x1 = (bf16*)out;
    bf16* x2 = x1 + H1SZ;

    prep_kernel<<<18 + 64 + 4096, 256, 0, stream>>>(
        (const float*)d_in[6],  (const float*)d_in[10],
        (const float*)d_in[16], (const float*)d_in[20],
        (const float*)d_in[26], (const float*)d_in[30],
        wpk,
        dur, idxb, mli, out_dr, out_ml,
        x, pitch, ptab, x1, x2);

    Args3 a1 = {
        {(const float*)d_in[7],  (const float*)d_in[17], (const float*)d_in[27]},
        {(const float*)d_in[8],  (const float*)d_in[18], (const float*)d_in[28]},
        {(const float*)d_in[9],  (const float*)d_in[19], (const float*)d_in[29]},
        {nullptr, nullptr, nullptr}, {nullptr, nullptr, nullptr},
        {nullptr, nullptr, nullptr}
    };
    Args3 a2 = {
        {(const float*)d_in[11], (const float*)d_in[21], (const float*)d_in[31]},
        {(const float*)d_in[12], (const float*)d_in[22], (const float*)d_in[32]},
        {(const float*)d_in[13], (const float*)d_in[23], (const float*)d_in[33]},
        {(const float*)d_in[14], (const float*)d_in[24], (const float*)d_in[34]},
        {(const float*)d_in[15], (const float*)d_in[25], (const float*)d_in[35]},
        {out_ld, out_p, out_e}
    };

    conv_fused<<<3 * 512, 256, 0, stream>>>(x1, x2, wpk, a1, a2, mask);

    gather_kernel<<<4096, 256, 0, stream>>>(x, ptab, pitch, etab, energy, idxb, mli, out);
}